// Round 1
// baseline (1716.426 us; speedup 1.0000x reference)
//
#include <hip/hip_runtime.h>

#define NB 16
#define TT 750
#define DD 2048
#define KK 8
#define CC 21
#define NT 12000

typedef __bf16 bf16;
typedef __attribute__((ext_vector_type(4))) float floatx4;
typedef __attribute__((ext_vector_type(8))) __bf16 bf16x8;
typedef __attribute__((ext_vector_type(4))) __bf16 bf16x4;

__device__ __forceinline__ float wave_allreduce_sum(float v) {
#pragma unroll
  for (int m = 32; m > 0; m >>= 1) v += __shfl_xor(v, m, 64);
  return v;
}

// ---------------- W transpose + bf16 convert: Wt[j][k] = W[k][j] ----------------
__global__ void k_prep_w(const float* __restrict__ W, bf16* __restrict__ Wt) {
  __shared__ float tile[32][33];
  int j0 = blockIdx.x * 32, k0 = blockIdx.y * 32;
  int tx = threadIdx.x, ty = threadIdx.y;
#pragma unroll
  for (int i = 0; i < 4; i++)
    tile[ty + 8 * i][tx] = W[(size_t)(k0 + ty + 8 * i) * DD + j0 + tx];
  __syncthreads();
#pragma unroll
  for (int i = 0; i < 4; i++)
    Wt[(size_t)(j0 + ty + 8 * i) * DD + k0 + tx] = (bf16)tile[tx][ty + 8 * i];
}

// ---------------- normalize ac_center rows (+fg as row 21), rows 22..31 zero ----
__global__ void k_ac_norm(const float* __restrict__ ac, const float* __restrict__ fg,
                          float* __restrict__ nacf, bf16* __restrict__ nacb) {
  int r = blockIdx.x;  // 0..31
  int tid = threadIdx.x;
  int d0 = tid * 8;
  if (r >= 22) {
#pragma unroll
    for (int j = 0; j < 8; j++) nacb[(size_t)r * DD + d0 + j] = (bf16)0.f;
    return;
  }
  const float* src = (r < 21) ? (ac + (size_t)r * DD) : fg;
  float v[8];
  floatx4 a = *(const floatx4*)(src + d0);
  floatx4 b = *(const floatx4*)(src + d0 + 4);
  v[0]=a.x; v[1]=a.y; v[2]=a.z; v[3]=a.w; v[4]=b.x; v[5]=b.y; v[6]=b.z; v[7]=b.w;
  float ss = 0.f;
#pragma unroll
  for (int j = 0; j < 8; j++) ss += v[j] * v[j];
  ss = wave_allreduce_sum(ss);
  __shared__ float sb[4];
  int lane = tid & 63, wid = tid >> 6;
  if (lane == 0) sb[wid] = ss;
  __syncthreads();
  float tot = sb[0] + sb[1] + sb[2] + sb[3];
  float inv = 1.f / (sqrtf(tot) + 1e-9f);
#pragma unroll
  for (int j = 0; j < 8; j++) {
    float nv = v[j] * inv;
    nacf[(size_t)r * DD + d0 + j] = nv;
    nacb[(size_t)r * DD + d0 + j] = (bf16)nv;
  }
}

// ---------------- embedding GEMM: C = relu(A@W + b), write fp32 + bf16 ----------
__global__ __launch_bounds__(256) void k_gemm(
    const float* __restrict__ A, const bf16* __restrict__ Bt,
    const float* __restrict__ bias,
    float* __restrict__ Cout, bf16* __restrict__ Cb) {
  __shared__ bf16 As[128 * 72];
  __shared__ bf16 Bs[128 * 72];
  int tid = threadIdx.x;
  int m0 = blockIdx.x * 128;
  int n0 = blockIdx.y * 128;
  int wid = tid >> 6, lane = tid & 63;
  int wm = (wid >> 1) * 64, wn = (wid & 1) * 64;
  int lrow = lane & 15, lko = (lane >> 4) * 8;
  floatx4 acc[4][4] = {};
  int af4 = tid & 15, arr = tid >> 4;
  int bf8 = tid & 7, brr = tid >> 3;
  for (int k0 = 0; k0 < DD; k0 += 64) {
#pragma unroll
    for (int s = 0; s < 8; s++) {
      int row = s * 16 + arr;
      int grow = m0 + row;
      floatx4 v = {0.f, 0.f, 0.f, 0.f};
      if (grow < NT) v = *(const floatx4*)(A + (size_t)grow * DD + k0 + af4 * 4);
      bf16x4 pv = {(bf16)v.x, (bf16)v.y, (bf16)v.z, (bf16)v.w};
      *(bf16x4*)(As + row * 72 + af4 * 4) = pv;
    }
#pragma unroll
    for (int s = 0; s < 4; s++) {
      int row = s * 32 + brr;
      bf16x8 v = *(const bf16x8*)(Bt + (size_t)(n0 + row) * DD + k0 + bf8 * 8);
      *(bf16x8*)(Bs + row * 72 + bf8 * 8) = v;
    }
    __syncthreads();
#pragma unroll
    for (int ks = 0; ks < 64; ks += 32) {
      bf16x8 af[4], bfr[4];
#pragma unroll
      for (int i = 0; i < 4; i++)
        af[i] = *(const bf16x8*)(As + (wm + i * 16 + lrow) * 72 + ks + lko);
#pragma unroll
      for (int j = 0; j < 4; j++)
        bfr[j] = *(const bf16x8*)(Bs + (wn + j * 16 + lrow) * 72 + ks + lko);
#pragma unroll
      for (int i = 0; i < 4; i++)
#pragma unroll
        for (int j = 0; j < 4; j++)
          acc[i][j] = __builtin_amdgcn_mfma_f32_16x16x32_bf16(af[i], bfr[j], acc[i][j], 0, 0, 0);
    }
    __syncthreads();
  }
  int quad = lane >> 4;
#pragma unroll
  for (int j = 0; j < 4; j++) {
    int col = n0 + wn + j * 16 + lrow;
    float bv = bias[col];
#pragma unroll
    for (int i = 0; i < 4; i++) {
#pragma unroll
      for (int r = 0; r < 4; r++) {
        int row = m0 + wm + i * 16 + quad * 4 + r;
        if (row < NT) {
          float v = acc[i][j][r] + bv;
          v = fmaxf(v, 0.f);
          Cout[(size_t)row * DD + col] = v;
          Cb[(size_t)row * DD + col] = (bf16)v;
        }
      }
    }
  }
}

// ---------------- per-row 1/(||row||+1e-9) over fp32 (NT x DD) ------------------
__global__ void k_rownorms(const float* __restrict__ X, float* __restrict__ inv) {
  int row = blockIdx.x;
  int tid = threadIdx.x, lane = tid & 63, wid = tid >> 6;
  const float* p = X + (size_t)row * DD + tid * 8;
  floatx4 a = *(const floatx4*)p;
  floatx4 b = *(const floatx4*)(p + 4);
  float ss = a.x*a.x + a.y*a.y + a.z*a.z + a.w*a.w + b.x*b.x + b.y*b.y + b.z*b.z + b.w*b.w;
  ss = wave_allreduce_sum(ss);
  __shared__ float sb[4];
  if (lane == 0) sb[wid] = ss;
  __syncthreads();
  if (tid == 0) {
    float tot = sb[0] + sb[1] + sb[2] + sb[3];
    inv[row] = 1.f / (sqrtf(tot) + 1e-9f);
  }
}

// ---------------- mu init: broadcast mu_param to all n ---------------------------
__global__ void k_mu_init(const float* __restrict__ mup, float* __restrict__ mu) {
  int idx = blockIdx.x * 256 + threadIdx.x;  // < 262144
  mu[idx] = mup[idx & 16383];
}

// ---------------- normalize mu rows (128 rows of DD) -----------------------------
__global__ void k_mu_norm(const float* __restrict__ mu, float* __restrict__ nmu) {
  int row = blockIdx.x;  // 0..127
  int tid = threadIdx.x, lane = tid & 63, wid = tid >> 6;
  const float* p = mu + (size_t)row * DD + tid * 8;
  float v[8];
  floatx4 a = *(const floatx4*)p;
  floatx4 b = *(const floatx4*)(p + 4);
  v[0]=a.x; v[1]=a.y; v[2]=a.z; v[3]=a.w; v[4]=b.x; v[5]=b.y; v[6]=b.z; v[7]=b.w;
  float ss = 0.f;
#pragma unroll
  for (int j = 0; j < 8; j++) ss += v[j] * v[j];
  ss = wave_allreduce_sum(ss);
  __shared__ float sb[4];
  if (lane == 0) sb[wid] = ss;
  __syncthreads();
  float tot = sb[0] + sb[1] + sb[2] + sb[3];
  float inv = 1.f / (sqrtf(tot) + 1e-9f);
  float* q = nmu + (size_t)row * DD + tid * 8;
#pragma unroll
  for (int j = 0; j < 8; j++) q[j] = v[j] * inv;
}

// ---------------- EM / RW-passA streaming pass -----------------------------------
// wave owns 2 clusters; x row staged via LDS; partials to global (no big atomics)
__global__ __launch_bounds__(256, 2) void k_em_pass(
    const bf16* __restrict__ Xb, const float* __restrict__ nmu,
    const float* __restrict__ invx,
    float* __restrict__ partial,   // [n][16][8][DD]
    float* __restrict__ rowsum,    // [n][8] (atomic)
    float* __restrict__ zout) {    // optional [n][8][TT]
  int n = blockIdx.x, ch = blockIdx.y, tid = threadIdx.x;
  int lane = tid & 63, wid = tid >> 6;
  int k0 = wid * 2;
  __shared__ bf16 xs[2048];
  __shared__ float red[8];
  const float* nm = nmu + ((size_t)n * 8) * DD;
  float mur[2][32];
#pragma unroll
  for (int kk = 0; kk < 2; kk++)
#pragma unroll
    for (int c = 0; c < 4; c++) {
      floatx4 a = *(const floatx4*)(nm + (k0 + kk) * DD + c * 512 + lane * 8);
      floatx4 b = *(const floatx4*)(nm + (k0 + kk) * DD + c * 512 + lane * 8 + 4);
      mur[kk][c*8+0]=a.x; mur[kk][c*8+1]=a.y; mur[kk][c*8+2]=a.z; mur[kk][c*8+3]=a.w;
      mur[kk][c*8+4]=b.x; mur[kk][c*8+5]=b.y; mur[kk][c*8+6]=b.z; mur[kk][c*8+7]=b.w;
    }
  float ar[2][32] = {};
  float rs0 = 0.f, rs1 = 0.f;
  const bf16* xrow = Xb + ((size_t)n * TT) * DD;
  for (int tt = 0; tt < 47; tt++) {
    int t = ch * 47 + tt;
    if (t >= TT) break;
    bf16x8 g = *(const bf16x8*)(xrow + (size_t)t * DD + tid * 8);
    *(bf16x8*)(xs + tid * 8) = g;
    __syncthreads();
    float xv[32];
#pragma unroll
    for (int c = 0; c < 4; c++) {
      bf16x8 v = *(const bf16x8*)(xs + c * 512 + lane * 8);
#pragma unroll
      for (int j = 0; j < 8; j++) xv[c * 8 + j] = (float)v[j];
    }
    float p0 = 0.f, p1 = 0.f;
#pragma unroll
    for (int i = 0; i < 32; i++) { p0 += mur[0][i] * xv[i]; p1 += mur[1][i] * xv[i]; }
#pragma unroll
    for (int m = 32; m > 0; m >>= 1) { p0 += __shfl_xor(p0, m, 64); p1 += __shfl_xor(p1, m, 64); }
    if (lane == 0) { red[k0] = p0; red[k0 + 1] = p1; }
    __syncthreads();
    float sc = invx[n * TT + t] * 5.f;
    float s[8];
#pragma unroll
    for (int k = 0; k < 8; k++) s[k] = red[k] * sc;
    float mx = s[0];
#pragma unroll
    for (int k = 1; k < 8; k++) mx = fmaxf(mx, s[k]);
    float e[8], se = 0.f;
#pragma unroll
    for (int k = 0; k < 8; k++) { e[k] = __expf(s[k] - mx); se += e[k]; }
    float inv = 1.f / se;
    float z0 = e[k0] * inv, z1 = e[k0 + 1] * inv;
    rs0 += z0; rs1 += z1;
#pragma unroll
    for (int i = 0; i < 32; i++) { ar[0][i] += z0 * xv[i]; ar[1][i] += z1 * xv[i]; }
    if (zout != nullptr && tid == 0) {
#pragma unroll
      for (int k = 0; k < 8; k++) zout[((size_t)n * 8 + k) * TT + t] = e[k] * inv;
    }
  }
  float* pb = partial + (((size_t)n * 16 + ch) * 8) * DD;
#pragma unroll
  for (int kk = 0; kk < 2; kk++)
#pragma unroll
    for (int c = 0; c < 4; c++) {
      floatx4 v = {ar[kk][c*8+0], ar[kk][c*8+1], ar[kk][c*8+2], ar[kk][c*8+3]};
      floatx4 w = {ar[kk][c*8+4], ar[kk][c*8+5], ar[kk][c*8+6], ar[kk][c*8+7]};
      *(floatx4*)(pb + (k0 + kk) * DD + c * 512 + lane * 8) = v;
      *(floatx4*)(pb + (k0 + kk) * DD + c * 512 + lane * 8 + 4) = w;
    }
  if (lane == 0) {
    atomicAdd(&rowsum[n * 8 + k0], rs0);
    atomicAdd(&rowsum[n * 8 + k0 + 1], rs1);
  }
}

// ---------------- reduce 16 chunk-partials; optional divide by rowsum ------------
__global__ void k_acc_reduce(const float* __restrict__ part, const float* __restrict__ rs,
                             float* __restrict__ dst, float* __restrict__ dst2) {
  int idx = blockIdx.x * 256 + threadIdx.x;  // < 262144
  int n = idx >> 14;
  int rem = idx & 16383;
  const float* p = part + ((size_t)n * 16) * 16384 + rem;
  float s = 0.f;
#pragma unroll
  for (int ch = 0; ch < 16; ch++) s += p[ch * 16384];
  if (rs != nullptr) { int k = rem >> 11; s = s / (rs[n * 8 + k] + 1e-9f); }
  dst[idx] = s;
  if (dst2 != nullptr) dst2[idx] = s;
}

// ---------------- Woodbury: 8x8 inverse + G = 0.5*(w*mu + Q) ---------------------
__global__ void k_woodbury(const float* __restrict__ z, const float* __restrict__ rowsum,
                           const float* __restrict__ S, const float* __restrict__ mu,
                           float* __restrict__ G) {
  int n = blockIdx.x, tid = threadIdx.x;
  __shared__ float VU[8][8];
  __shared__ float Mi[8][8];
  __shared__ float invrs[8];
  if (tid < 8) invrs[tid] = 1.f / (rowsum[n * 8 + tid] + 1e-9f);
  __syncthreads();
  if (tid < 64) {
    int j = tid >> 3, k = tid & 7;
    const float* zj = z + ((size_t)n * 8 + j) * TT;
    const float* zk = z + ((size_t)n * 8 + k) * TT;
    float s = 0.f;
    for (int t = 0; t < TT; t++) s += zj[t] * zk[t];
    VU[j][k] = s * invrs[j];
  }
  __syncthreads();
  if (tid == 0) {
    float M[8][16];
    for (int i = 0; i < 8; i++)
      for (int jj = 0; jj < 8; jj++) {
        M[i][jj] = ((i == jj) ? 1.f : 0.f) - 0.25f * VU[i][jj];
        M[i][8 + jj] = (i == jj) ? 1.f : 0.f;
      }
    for (int c = 0; c < 8; c++) {
      float pv = 1.f / M[c][c];
      for (int jj = 0; jj < 16; jj++) M[c][jj] *= pv;
      for (int rr = 0; rr < 8; rr++)
        if (rr != c) {
          float f = M[rr][c];
          for (int jj = 0; jj < 16; jj++) M[rr][jj] -= f * M[c][jj];
        }
    }
    for (int i = 0; i < 8; i++)
      for (int jj = 0; jj < 8; jj++) Mi[i][jj] = M[i][8 + jj];
  }
  __syncthreads();
  const float* mun = mu + ((size_t)n * 8) * DD;
  const float* Sn = S + ((size_t)n * 8) * DD;
  float* Gn = G + ((size_t)n * 8) * DD;
  for (int d = tid; d < DD; d += 256) {
    float m[8], P[8];
#pragma unroll
    for (int k = 0; k < 8; k++) m[k] = mun[k * DD + d];
#pragma unroll
    for (int k = 0; k < 8; k++) {
      float s = 0.f;
#pragma unroll
      for (int jj = 0; jj < 8; jj++) s += VU[k][jj] * m[jj];
      P[k] = 0.5f * s + Sn[k * DD + d] * invrs[k];
    }
#pragma unroll
    for (int jj = 0; jj < 8; jj++) {
      float s = 0.f;
#pragma unroll
      for (int k = 0; k < 8; k++) s += Mi[jj][k] * P[k];
      Gn[jj * DD + d] = 0.5f * (0.5f * m[jj] + 0.25f * s);
    }
  }
}

// ---------------- RW pass C: refined = 0.5*x + Z^T G; bf16 out + row norms -------
__global__ __launch_bounds__(256) void k_rw_passC(
    const bf16* __restrict__ Xb, const float* __restrict__ z,
    const float* __restrict__ G, bf16* __restrict__ refb,
    float* __restrict__ invr) {
  int n = blockIdx.x, ch = blockIdx.y, tid = threadIdx.x;
  int lane = tid & 63, wid = tid >> 6;
  int d0 = tid * 8;
  const float* Gn = G + ((size_t)n * 8) * DD;
  float gr[8][8];
#pragma unroll
  for (int k = 0; k < 8; k++) {
    floatx4 a = *(const floatx4*)(Gn + k * DD + d0);
    floatx4 b = *(const floatx4*)(Gn + k * DD + d0 + 4);
    gr[k][0]=a.x; gr[k][1]=a.y; gr[k][2]=a.z; gr[k][3]=a.w;
    gr[k][4]=b.x; gr[k][5]=b.y; gr[k][6]=b.z; gr[k][7]=b.w;
  }
  __shared__ float red[2][4];
  const bf16* xrow = Xb + ((size_t)n * TT) * DD;
  for (int tt = 0; tt < 47; tt++) {
    int t = ch * 47 + tt;
    if (t >= TT) break;
    float zt[8];
#pragma unroll
    for (int k = 0; k < 8; k++) zt[k] = z[((size_t)n * 8 + k) * TT + t];
    bf16x8 x8 = *(const bf16x8*)(xrow + (size_t)t * DD + d0);
    float r[8];
#pragma unroll
    for (int j = 0; j < 8; j++) {
      float s = 0.5f * (float)x8[j];
#pragma unroll
      for (int k = 0; k < 8; k++) s += zt[k] * gr[k][j];
      r[j] = s;
    }
    bf16x8 ro;
#pragma unroll
    for (int j = 0; j < 8; j++) ro[j] = (bf16)r[j];
    *(bf16x8*)(refb + ((size_t)(n * TT + t)) * DD + d0) = ro;
    float ss = 0.f;
#pragma unroll
    for (int j = 0; j < 8; j++) ss += r[j] * r[j];
    ss = wave_allreduce_sum(ss);
    int par = tt & 1;
    if (lane == 0) red[par][wid] = ss;
    __syncthreads();
    if (tid == 0) {
      float tot = red[par][0] + red[par][1] + red[par][2] + red[par][3];
      invr[n * TT + t] = 1.f / (sqrtf(tot) + 1e-9f);
    }
  }
}

// ---------------- mu_pred: softmax_c(20 * nmu . nac) -----------------------------
__global__ void k_mu_pred(const float* __restrict__ nmu, const float* __restrict__ nacf,
                          float* __restrict__ outp) {
  int b = blockIdx.x;  // 0..127
  int tid = threadIdx.x, lane = tid & 63, wid = tid >> 6;
  const float* v = nmu + (size_t)b * DD;
  __shared__ float scr[21];
  for (int c = wid; c < 21; c += 4) {
    const float* a = nacf + (size_t)c * DD;
    float s = 0.f;
    for (int i = lane; i < DD; i += 64) s += v[i] * a[i];
    s = wave_allreduce_sum(s);
    if (lane == 0) scr[c] = s * 20.f;
  }
  __syncthreads();
  if (tid == 0) {
    float mx = scr[0];
    for (int c = 1; c < 21; c++) mx = fmaxf(mx, scr[c]);
    float se = 0.f;
    for (int c = 0; c < 21; c++) se += __expf(scr[c] - mx);
    float inv = 1.f / se;
    for (int c = 0; c < 21; c++) outp[(size_t)b * 21 + c] = __expf(scr[c] - mx) * inv;
  }
}

// ---------------- prediction pass1: skinny MFMA GEMM (N=32), sigmoid/att sums ----
__global__ __launch_bounds__(256) void k_pred_p1(
    const bf16* __restrict__ Xb, const bf16* __restrict__ nacb,
    const float* __restrict__ invn,
    float* __restrict__ out_frm, float* __restrict__ out_att,
    float* __restrict__ natt, float* __restrict__ att_sums) {
  __shared__ bf16 As[64 * 72];
  __shared__ bf16 Bs[32 * 72];
  __shared__ float ssum[2][32];
  int tid = threadIdx.x, lane = tid & 63, wid = tid >> 6;
  int m0 = blockIdx.x * 64;
  if (tid < 64) ssum[tid >> 5][tid & 31] = 0.f;
  int lrow = lane & 15, lko = (lane >> 4) * 8;
  floatx4 acc[2] = {};
  for (int k0 = 0; k0 < DD; k0 += 64) {
#pragma unroll
    for (int s = 0; s < 2; s++) {
      int idx = s * 256 + tid;
      int row = idx >> 3, f8 = idx & 7;
      int grow = m0 + row;
      bf16x8 v = {};
      if (grow < NT) v = *(const bf16x8*)(Xb + (size_t)grow * DD + k0 + f8 * 8);
      *(bf16x8*)(As + row * 72 + f8 * 8) = v;
    }
    {
      int row = tid >> 3, f8 = tid & 7;
      bf16x8 v = *(const bf16x8*)(nacb + (size_t)row * DD + k0 + f8 * 8);
      *(bf16x8*)(Bs + row * 72 + f8 * 8) = v;
    }
    __syncthreads();
#pragma unroll
    for (int ks = 0; ks < 64; ks += 32) {
      bf16x8 a = *(const bf16x8*)(As + (wid * 16 + lrow) * 72 + ks + lko);
      bf16x8 b0 = *(const bf16x8*)(Bs + (lrow)*72 + ks + lko);
      bf16x8 b1 = *(const bf16x8*)(Bs + (16 + lrow) * 72 + ks + lko);
      acc[0] = __builtin_amdgcn_mfma_f32_16x16x32_bf16(a, b0, acc[0], 0, 0, 0);
      acc[1] = __builtin_amdgcn_mfma_f32_16x16x32_bf16(a, b1, acc[1], 0, 0, 0);
    }
    __syncthreads();
  }
  int quad = lane >> 4;
  int nbase = m0 / TT;
#pragma unroll
  for (int j = 0; j < 2; j++) {
    int c = j * 16 + lrow;
#pragma unroll
    for (int r = 0; r < 4; r++) {
      int row = m0 + wid * 16 + quad * 4 + r;
      if (row < NT && c < 22) {
        float s = acc[j][r] * invn[row] * 20.f;
        float sg = 1.f / (1.f + __expf(-s));
        int n_loc = row / TT - nbase;
        if (c < 21) out_frm[(size_t)row * 21 + c] = s;
        else out_att[row] = sg;
        natt[(size_t)row * 22 + c] = sg;
        atomicAdd(&ssum[n_loc][c], sg);
      }
    }
  }
  __syncthreads();
  if (tid < 64) {
    int nl = tid >> 5, c = tid & 31;
    int nn = nbase + nl;
    if (c < 22 && nn < NB) {
      float v = ssum[nl][c];
      if (v != 0.f) atomicAdd(&att_sums[nn * 22 + c], v);
    }
  }
}

// ---------------- natt normalize -------------------------------------------------
__global__ void k_natt_norm(float* __restrict__ natt, const float* __restrict__ sums) {
  int idx = blockIdx.x * 256 + threadIdx.x;
  if (idx >= NT * 22) return;
  int row = idx / 22;
  int c = idx - row * 22;
  int n = row / TT;
  natt[idx] = natt[idx] / (sums[n * 22 + c] + 1e-5f);
}

// ---------------- prediction pass2: feats partials (register acc) ----------------
__global__ __launch_bounds__(256) void k_pred_p2(
    const bf16* __restrict__ Xb, const float* __restrict__ natt,
    float* __restrict__ partF) {  // [n][8][22][DD]
  int n = blockIdx.x, dh = blockIdx.y, tc = blockIdx.z, tid = threadIdx.x;
  int d = dh * 1024 + tid * 4;
  float ac[22][4] = {};
  __shared__ float sw[2][22];
  const bf16* xrow = Xb + ((size_t)n * TT) * DD;
  for (int tt = 0; tt < 94; tt++) {
    int t = tc * 94 + tt;
    if (t >= TT) break;
    int par = tt & 1;
    if (tid < 22) sw[par][tid] = natt[((size_t)(n * TT + t)) * 22 + tid];
    __syncthreads();
    bf16x4 x4 = *(const bf16x4*)(xrow + (size_t)t * DD + d);
    float xv[4] = {(float)x4[0], (float)x4[1], (float)x4[2], (float)x4[3]};
#pragma unroll
    for (int c = 0; c < 22; c++) {
      float w = sw[par][c];
#pragma unroll
      for (int j = 0; j < 4; j++) ac[c][j] += w * xv[j];
    }
  }
  float* pb = partF + (((size_t)(n * 8 + tc)) * 22) * DD + d;
#pragma unroll
  for (int c = 0; c < 22; c++) {
    floatx4 v = {ac[c][0], ac[c][1], ac[c][2], ac[c][3]};
    *(floatx4*)(pb + (size_t)c * DD) = v;
  }
}

// ---------------- reduce feats partials ------------------------------------------
__global__ void k_feat_finish(const float* __restrict__ partF, float* __restrict__ feats) {
  int idx = blockIdx.x * 256 + threadIdx.x;
  if (idx >= NB * 22 * DD) return;
  int n = idx / (22 * DD);
  int rem = idx - n * (22 * DD);
  const float* p = partF + ((size_t)n * 8) * (22 * DD) + rem;
  float s = 0.f;
#pragma unroll
  for (int tc = 0; tc < 8; tc++) s += p[(size_t)tc * 22 * DD];
  feats[idx] = s;
}

// ---------------- final scores + softmax -----------------------------------------
__global__ void k_pred_final(const float* __restrict__ feats, const float* __restrict__ nacf,
                             float* __restrict__ oca, float* __restrict__ ocw) {
  int n = blockIdx.x, tid = threadIdx.x, lane = tid & 63, wid = tid >> 6;
  const float* fn = feats + (size_t)n * 22 * DD;
  __shared__ float rnorm[22];
  __shared__ float scr[42];
  for (int r = wid; r < 22; r += 4) {
    const float* fv = fn + (size_t)r * DD;
    float s = 0.f;
    for (int i = lane; i < DD; i += 64) { float x = fv[i]; s += x * x; }
    s = wave_allreduce_sum(s);
    if (lane == 0) rnorm[r] = 1.f / (sqrtf(s) + 1e-9f);
  }
  __syncthreads();
  for (int idx = wid; idx < 42; idx += 4) {
    int c = (idx < 21) ? idx : (idx - 21);
    int fr = (idx < 21) ? c : 21;
    const float* fv = fn + (size_t)fr * DD;
    const float* av = nacf + (size_t)c * DD;
    float s = 0.f;
    for (int i = lane; i < DD; i += 64) s += fv[i] * av[i];
    s = wave_allreduce_sum(s);
    if (lane == 0) scr[idx] = s * 20.f * rnorm[fr];
  }
  __syncthreads();
  if (tid < 2) {
    int base = (tid == 0) ? 21 : 0;  // tid0 -> ca, tid1 -> cw
    float* dst = ((tid == 0) ? oca : ocw) + (size_t)n * 21;
    float mx = scr[base];
    for (int c = 1; c < 21; c++) mx = fmaxf(mx, scr[base + c]);
    float se = 0.f;
    for (int c = 0; c < 21; c++) se += __expf(scr[base + c] - mx);
    float inv = 1.f / se;
    for (int c = 0; c < 21; c++) dst[c] = __expf(scr[base + c] - mx) * inv;
  }
}

extern "C" void kernel_launch(void* const* d_in, const int* in_sizes, int n_in,
                              void* d_out, int out_size, void* d_ws, size_t ws_size,
                              hipStream_t stream) {
  const float* x_in = (const float*)d_in[0];
  const float* W = (const float*)d_in[1];
  const float* bemb = (const float*)d_in[2];
  const float* mup = (const float*)d_in[3];
  const float* ac = (const float*)d_in[4];
  const float* fg = (const float*)d_in[5];
  float* out = (float*)d_out;

  char* ws = (char*)d_ws;
  bf16* Wt = (bf16*)ws;                          // 8,388,608 B
  bf16* Xb = (bf16*)(ws + 8388608);              // 49,152,000 B
  bf16* Rb = (bf16*)(ws + 57540608);             // 49,152,000 B
  bf16* nacb = (bf16*)(ws + 106692608);          // 131,072 B
  float* fb = (float*)(ws + 106823680);
  float* nacf = fb;                    // 45,056
  float* mu = nacf + 45056;            // 262,144
  float* nmu = mu + 262144;            // 262,144
  float* accS = nmu + 262144;          // 262,144
  float* G = accS + 262144;            // 262,144
  float* invx = G + 262144;            // 12,032
  float* invr = invx + 12032;          // 12,032
  float* rowsum = invr + 12032;        // 128
  float* z = rowsum + 128;             // 96,000
  float* natt = z + 96000;             // 264,000
  float* asums = natt + 264000;        // 512
  float* partA = asums + 512;          // 5,767,168 (shared with partF)
  float* partF = partA;
  float* feats = partA + 5767168;      // 720,896

  float* o_ca = out;
  float* o_cw = out + 336;
  float* o_att = out + 672;
  float* o_frm = out + 12672;
  float* m_ca = out + 264672;
  float* m_cw = out + 265008;
  float* m_att = out + 265344;
  float* m_frm = out + 277344;
  float* x_out = out + 529344;
  float* mu_out = out + 25105344;
  float* mup_out = out + 25367488;

  k_prep_w<<<dim3(64, 64), dim3(32, 8), 0, stream>>>(W, Wt);
  k_ac_norm<<<32, 256, 0, stream>>>(ac, fg, nacf, nacb);
  k_gemm<<<dim3(94, 16), 256, 0, stream>>>(x_in, Wt, bemb, x_out, Xb);
  k_rownorms<<<NT, 256, 0, stream>>>(x_out, invx);
  k_mu_init<<<1024, 256, 0, stream>>>(mup, mu);
  for (int it = 0; it < 5; it++) {
    hipMemsetAsync(rowsum, 0, 128 * sizeof(float), stream);
    k_mu_norm<<<128, 256, 0, stream>>>(mu, nmu);
    k_em_pass<<<dim3(16, 16), 256, 0, stream>>>(Xb, nmu, invx, partA, rowsum, nullptr);
    k_acc_reduce<<<1024, 256, 0, stream>>>(partA, rowsum, mu, (it == 4) ? mu_out : nullptr);
  }
  k_mu_norm<<<128, 256, 0, stream>>>(mu, nmu);
  hipMemsetAsync(rowsum, 0, 128 * sizeof(float), stream);
  k_em_pass<<<dim3(16, 16), 256, 0, stream>>>(Xb, nmu, invx, partA, rowsum, z);
  k_acc_reduce<<<1024, 256, 0, stream>>>(partA, nullptr, accS, nullptr);
  k_woodbury<<<16, 256, 0, stream>>>(z, rowsum, accS, mu, G);
  k_rw_passC<<<dim3(16, 16), 256, 0, stream>>>(Xb, z, G, Rb, invr);
  k_mu_pred<<<128, 256, 0, stream>>>(nmu, nacf, mup_out);
  // o-phase (on x)
  hipMemsetAsync(asums, 0, 512 * sizeof(float), stream);
  k_pred_p1<<<188, 256, 0, stream>>>(Xb, nacb, invx, o_frm, o_att, natt, asums);
  k_natt_norm<<<1032, 256, 0, stream>>>(natt, asums);
  k_pred_p2<<<dim3(16, 2, 8), 256, 0, stream>>>(Xb, natt, partF);
  k_feat_finish<<<2816, 256, 0, stream>>>(partF, feats);
  k_pred_final<<<16, 256, 0, stream>>>(feats, nacf, o_ca, o_cw);
  // m-phase (on refined)
  hipMemsetAsync(asums, 0, 512 * sizeof(float), stream);
  k_pred_p1<<<188, 256, 0, stream>>>(Rb, nacb, invr, m_frm, m_att, natt, asums);
  k_natt_norm<<<1032, 256, 0, stream>>>(natt, asums);
  k_pred_p2<<<dim3(16, 2, 8), 256, 0, stream>>>(Rb, natt, partF);
  k_feat_finish<<<2816, 256, 0, stream>>>(partF, feats);
  k_pred_final<<<16, 256, 0, stream>>>(feats, nacf, m_ca, m_cw);
}

// Round 2
// 1372.968 us; speedup vs baseline: 1.2502x; 1.2502x over previous
//
#include <hip/hip_runtime.h>

#define NB 16
#define TT 750
#define DD 2048
#define KK 8
#define CC 21
#define NT 12000

typedef __bf16 bf16;
typedef __attribute__((ext_vector_type(4))) float floatx4;
typedef __attribute__((ext_vector_type(8))) __bf16 bf16x8;
typedef __attribute__((ext_vector_type(4))) __bf16 bf16x4;

__device__ __forceinline__ float wave_allreduce_sum(float v) {
#pragma unroll
  for (int m = 32; m > 0; m >>= 1) v += __shfl_xor(v, m, 64);
  return v;
}

__device__ __forceinline__ void async_lds16(const bf16* g, bf16* l) {
  __builtin_amdgcn_global_load_lds(
      (const __attribute__((address_space(1))) void*)(g),
      (__attribute__((address_space(3))) void*)(l), 16, 0, 0);
}

// ---------------- W transpose + bf16 convert: Wt[j][k] = W[k][j] ----------------
__global__ void k_prep_w(const float* __restrict__ W, bf16* __restrict__ Wt) {
  __shared__ float tile[32][33];
  int j0 = blockIdx.x * 32, k0 = blockIdx.y * 32;
  int tx = threadIdx.x, ty = threadIdx.y;
#pragma unroll
  for (int i = 0; i < 4; i++)
    tile[ty + 8 * i][tx] = W[(size_t)(k0 + ty + 8 * i) * DD + j0 + tx];
  __syncthreads();
#pragma unroll
  for (int i = 0; i < 4; i++)
    Wt[(size_t)(j0 + ty + 8 * i) * DD + k0 + tx] = (bf16)tile[tx][ty + 8 * i];
}

// ---------------- x -> bf16 (rows >= NT zero-padded to 12032) -------------------
__global__ void k_xbf16(const float* __restrict__ x, bf16* __restrict__ Ab) {
  size_t base = ((size_t)blockIdx.x * 256 + threadIdx.x) * 8;
  int row = (int)(base >> 11);
  bf16x8 o = {};
  if (row < NT) {
    floatx4 a = *(const floatx4*)(x + base);
    floatx4 b = *(const floatx4*)(x + base + 4);
    o[0] = (bf16)a.x; o[1] = (bf16)a.y; o[2] = (bf16)a.z; o[3] = (bf16)a.w;
    o[4] = (bf16)b.x; o[5] = (bf16)b.y; o[6] = (bf16)b.z; o[7] = (bf16)b.w;
  }
  *(bf16x8*)(Ab + base) = o;
}

// ---------------- normalize ac_center rows (+fg as row 21), rows 22..31 zero ----
__global__ void k_ac_norm(const float* __restrict__ ac, const float* __restrict__ fg,
                          float* __restrict__ nacf, bf16* __restrict__ nacb) {
  int r = blockIdx.x;  // 0..31
  int tid = threadIdx.x;
  int d0 = tid * 8;
  if (r >= 22) {
#pragma unroll
    for (int j = 0; j < 8; j++) nacb[(size_t)r * DD + d0 + j] = (bf16)0.f;
    return;
  }
  const float* src = (r < 21) ? (ac + (size_t)r * DD) : fg;
  float v[8];
  floatx4 a = *(const floatx4*)(src + d0);
  floatx4 b = *(const floatx4*)(src + d0 + 4);
  v[0]=a.x; v[1]=a.y; v[2]=a.z; v[3]=a.w; v[4]=b.x; v[5]=b.y; v[6]=b.z; v[7]=b.w;
  float ss = 0.f;
#pragma unroll
  for (int j = 0; j < 8; j++) ss += v[j] * v[j];
  ss = wave_allreduce_sum(ss);
  __shared__ float sb[4];
  int lane = tid & 63, wid = tid >> 6;
  if (lane == 0) sb[wid] = ss;
  __syncthreads();
  float tot = sb[0] + sb[1] + sb[2] + sb[3];
  float inv = 1.f / (sqrtf(tot) + 1e-9f);
#pragma unroll
  for (int j = 0; j < 8; j++) {
    float nv = v[j] * inv;
    nacf[(size_t)r * DD + d0 + j] = nv;
    nacb[(size_t)r * DD + d0 + j] = (bf16)nv;
  }
}

// ---------------- embedding GEMM (m97 structure) + fused row sum-of-squares -----
__global__ __launch_bounds__(256) void k_gemm(
    const bf16* __restrict__ Ab, const bf16* __restrict__ Bt,
    const float* __restrict__ bias,
    float* __restrict__ Cout, bf16* __restrict__ Cb, float* __restrict__ rowsq) {
  __shared__ bf16 As[128 * 64];
  __shared__ bf16 Bs[128 * 64];
  int tid = threadIdx.x;
  int n0 = blockIdx.x * 128;  // grid.x = 16
  int m0 = blockIdx.y * 128;  // grid.y = 94
  int wid = tid >> 6, lane = tid & 63;
  int wm = (wid >> 1) * 64, wn = (wid & 1) * 64;
  int lrow = lane & 15, lko = (lane >> 4) * 8;
  floatx4 acc[4][4] = {};
  int crow = tid >> 3, c8 = (tid & 7) * 8;
  const bf16* gA = Ab + (size_t)(m0 + crow) * DD + c8;
  const bf16* gB = Bt + (size_t)(n0 + crow) * DD + c8;
  bf16* lA = As + tid * 8;
  bf16* lB = Bs + tid * 8;
  for (int k0 = 0; k0 < DD; k0 += 64) {
#pragma unroll
    for (int s = 0; s < 4; s++)
      async_lds16(gA + (size_t)(32 * s) * DD + k0, lA + 2048 * s);
#pragma unroll
    for (int s = 0; s < 4; s++)
      async_lds16(gB + (size_t)(32 * s) * DD + k0, lB + 2048 * s);
    __syncthreads();
#pragma unroll
    for (int ks = 0; ks < 64; ks += 32) {
      bf16x8 af[4], bfr[4];
#pragma unroll
      for (int i = 0; i < 4; i++)
        af[i] = *(const bf16x8*)(As + (wm + i * 16 + lrow) * 64 + ks + lko);
#pragma unroll
      for (int j = 0; j < 4; j++)
        bfr[j] = *(const bf16x8*)(Bs + (wn + j * 16 + lrow) * 64 + ks + lko);
#pragma unroll
      for (int i = 0; i < 4; i++)
#pragma unroll
        for (int j = 0; j < 4; j++)
          acc[i][j] = __builtin_amdgcn_mfma_f32_16x16x32_bf16(af[i], bfr[j], acc[i][j], 0, 0, 0);
    }
    __syncthreads();
  }
  int quad = lane >> 4;
  float bv[4];
#pragma unroll
  for (int j = 0; j < 4; j++) bv[j] = bias[n0 + wn + j * 16 + lrow];
#pragma unroll
  for (int i = 0; i < 4; i++) {
#pragma unroll
    for (int r = 0; r < 4; r++) {
      int row = m0 + wm + i * 16 + quad * 4 + r;
      bool ok = (row < NT);
      float sq = 0.f;
#pragma unroll
      for (int j = 0; j < 4; j++) {
        int col = n0 + wn + j * 16 + lrow;
        float v = acc[i][j][r] + bv[j];
        v = fmaxf(v, 0.f);
        if (ok) {
          Cout[(size_t)row * DD + col] = v;
          Cb[(size_t)row * DD + col] = (bf16)v;
        }
        sq += v * v;
      }
#pragma unroll
      for (int m = 1; m < 16; m <<= 1) sq += __shfl_xor(sq, m, 64);
      if (ok && lrow == 0) atomicAdd(&rowsq[row], sq);
    }
  }
}

// ---------------- invx from rowsq ------------------------------------------------
__global__ void k_invx(const float* __restrict__ rowsq, float* __restrict__ invx) {
  int i = blockIdx.x * 256 + threadIdx.x;
  if (i < NT) invx[i] = 1.f / (sqrtf(rowsq[i]) + 1e-9f);
}

// ---------------- iter-0 nmu: l2n(mu_param[k]) broadcast to all n ----------------
__global__ void k_mu_norm0(const float* __restrict__ mup, float* __restrict__ nmu) {
  int b = blockIdx.x;  // n*8+k
  int k = b & 7;
  int tid = threadIdx.x, lane = tid & 63, wid = tid >> 6;
  const float* p = mup + (size_t)k * DD + tid * 8;
  float v[8];
  floatx4 a = *(const floatx4*)p;
  floatx4 c = *(const floatx4*)(p + 4);
  v[0]=a.x; v[1]=a.y; v[2]=a.z; v[3]=a.w; v[4]=c.x; v[5]=c.y; v[6]=c.z; v[7]=c.w;
  float ss = 0.f;
#pragma unroll
  for (int j = 0; j < 8; j++) ss += v[j] * v[j];
  ss = wave_allreduce_sum(ss);
  __shared__ float sb[4];
  if (lane == 0) sb[wid] = ss;
  __syncthreads();
  float tot = sb[0] + sb[1] + sb[2] + sb[3];
  float inv = 1.f / (sqrtf(tot) + 1e-9f);
  float* q = nmu + (size_t)b * DD + tid * 8;
#pragma unroll
  for (int j = 0; j < 8; j++) q[j] = v[j] * inv;
}

// ---------------- EM streaming pass: wave-per-cluster, 8 waves -------------------
__global__ __launch_bounds__(512) void k_em_pass(
    const bf16* __restrict__ Xb, const float* __restrict__ nmu,
    const float* __restrict__ invx,
    float* __restrict__ partial,   // [n][32][8][DD]
    float* __restrict__ rowsum,    // [n][8] (atomic, pre-zeroed)
    float* __restrict__ zout) {    // optional [n][8][TT]
  int n = blockIdx.x, ch = blockIdx.y, tid = threadIdx.x;
  int lane = tid & 63, w = tid >> 6;  // w = cluster
  __shared__ uint32_t xs[1024];
  __shared__ float red[8];
  const float* nm = nmu + (size_t)(n * 8 + w) * DD;
  float mur[32];
#pragma unroll
  for (int j = 0; j < 16; j++) {
    float2 mv = *(const float2*)(nm + 2 * lane + 128 * j);
    mur[2 * j] = mv.x; mur[2 * j + 1] = mv.y;
  }
  float ar[32] = {};
  float rs = 0.f;
  const bf16* xrow = Xb + (size_t)n * TT * DD;
  for (int tt = 0; tt < 24; tt++) {
    int t = ch * 24 + tt;
    if (t >= TT) break;
    uint2 g = *(const uint2*)(xrow + (size_t)t * DD + tid * 4);
    *(uint2*)&xs[tid * 2] = g;
    __syncthreads();
    float xv[32];
    float p = 0.f;
#pragma unroll
    for (int j = 0; j < 16; j++) {
      uint32_t u = xs[lane + 64 * j];
      float lo = __uint_as_float(u << 16);
      float hi = __uint_as_float(u & 0xffff0000u);
      xv[2 * j] = lo; xv[2 * j + 1] = hi;
      p += mur[2 * j] * lo + mur[2 * j + 1] * hi;
    }
    p = wave_allreduce_sum(p);
    if (lane == 0) red[w] = p;
    __syncthreads();
    float sc = invx[n * TT + t] * 5.f;
    float s[8];
#pragma unroll
    for (int k = 0; k < 8; k++) s[k] = red[k] * sc;
    float mx = s[0];
#pragma unroll
    for (int k = 1; k < 8; k++) mx = fmaxf(mx, s[k]);
    float se = 0.f;
#pragma unroll
    for (int k = 0; k < 8; k++) se += __expf(s[k] - mx);
    float z = __expf(s[w] - mx) / se;
    rs += z;
#pragma unroll
    for (int i = 0; i < 32; i++) ar[i] += z * xv[i];
    if (zout != nullptr && lane == 0) zout[(size_t)(n * 8 + w) * TT + t] = z;
  }
  float* pb = partial + ((size_t)(n * 32 + ch) * 8 + w) * DD;
#pragma unroll
  for (int j = 0; j < 16; j++) {
    float2 v = {ar[2 * j], ar[2 * j + 1]};
    *(float2*)(pb + 2 * lane + 128 * j) = v;
  }
  if (lane == 0) atomicAdd(&rowsum[n * 8 + w], rs);
}

// ---------------- reduce chunk partials + optional divide + fused l2-norm --------
__global__ void k_mu_finish(const float* __restrict__ partial, const float* __restrict__ rs,
                            float* __restrict__ raw_out, float* __restrict__ mu_ws,
                            float* __restrict__ mu_out, float* __restrict__ nmu_out) {
  int b = blockIdx.x;  // n*8+k
  int n = b >> 3, k = b & 7;
  int tid = threadIdx.x, lane = tid & 63, wid = tid >> 6;
  int d0 = tid * 8;
  const float* p = partial + ((size_t)n * 32 * 8 + k) * DD + d0;
  float s[8] = {};
  for (int ch = 0; ch < 32; ch++) {
    floatx4 a = *(const floatx4*)(p + (size_t)ch * 8 * DD);
    floatx4 c = *(const floatx4*)(p + (size_t)ch * 8 * DD + 4);
    s[0]+=a.x; s[1]+=a.y; s[2]+=a.z; s[3]+=a.w; s[4]+=c.x; s[5]+=c.y; s[6]+=c.z; s[7]+=c.w;
  }
  float m[8];
  float invr = (rs != nullptr) ? 1.f / (rs[b] + 1e-9f) : 1.f;
#pragma unroll
  for (int j = 0; j < 8; j++) m[j] = s[j] * invr;
  if (raw_out != nullptr) {
#pragma unroll
    for (int j = 0; j < 8; j++) raw_out[(size_t)b * DD + d0 + j] = s[j];
  }
  if (mu_ws != nullptr) {
#pragma unroll
    for (int j = 0; j < 8; j++) {
      mu_ws[(size_t)b * DD + d0 + j] = m[j];
      mu_out[(size_t)b * DD + d0 + j] = m[j];
    }
  }
  if (nmu_out != nullptr) {
    float ss = 0.f;
#pragma unroll
    for (int j = 0; j < 8; j++) ss += m[j] * m[j];
    ss = wave_allreduce_sum(ss);
    __shared__ float sb[4];
    if (lane == 0) sb[wid] = ss;
    __syncthreads();
    float tot = sb[0] + sb[1] + sb[2] + sb[3];
    float inv = 1.f / (sqrtf(tot) + 1e-9f);
#pragma unroll
    for (int j = 0; j < 8; j++) nmu_out[(size_t)b * DD + d0 + j] = m[j] * inv;
  }
}

// ---------------- Woodbury: 8x8 inverse + G ---------------------------------------
__global__ void k_woodbury(const float* __restrict__ z, const float* __restrict__ rowsum,
                           const float* __restrict__ S, const float* __restrict__ mu,
                           float* __restrict__ G) {
  int n = blockIdx.x, tid = threadIdx.x;
  __shared__ float VU[8][8];
  __shared__ float Mi[8][8];
  __shared__ float invrs[8];
  if (tid < 8) invrs[tid] = 1.f / (rowsum[n * 8 + tid] + 1e-9f);
  __syncthreads();
  if (tid < 64) {
    int j = tid >> 3, k = tid & 7;
    const float* zj = z + ((size_t)n * 8 + j) * TT;
    const float* zk = z + ((size_t)n * 8 + k) * TT;
    float s = 0.f;
    for (int t = 0; t < TT; t++) s += zj[t] * zk[t];
    VU[j][k] = s * invrs[j];
  }
  __syncthreads();
  if (tid == 0) {
    float M[8][16];
    for (int i = 0; i < 8; i++)
      for (int jj = 0; jj < 8; jj++) {
        M[i][jj] = ((i == jj) ? 1.f : 0.f) - 0.25f * VU[i][jj];
        M[i][8 + jj] = (i == jj) ? 1.f : 0.f;
      }
    for (int c = 0; c < 8; c++) {
      float pv = 1.f / M[c][c];
      for (int jj = 0; jj < 16; jj++) M[c][jj] *= pv;
      for (int rr = 0; rr < 8; rr++)
        if (rr != c) {
          float f = M[rr][c];
          for (int jj = 0; jj < 16; jj++) M[rr][jj] -= f * M[c][jj];
        }
    }
    for (int i = 0; i < 8; i++)
      for (int jj = 0; jj < 8; jj++) Mi[i][jj] = M[i][8 + jj];
  }
  __syncthreads();
  const float* mun = mu + (size_t)n * 8 * DD;
  const float* Sn = S + (size_t)n * 8 * DD;
  float* Gn = G + (size_t)n * 8 * DD;
  for (int d = tid; d < DD; d += 256) {
    float m[8], P[8];
#pragma unroll
    for (int k = 0; k < 8; k++) m[k] = mun[k * DD + d];
#pragma unroll
    for (int k = 0; k < 8; k++) {
      float s = 0.f;
#pragma unroll
      for (int jj = 0; jj < 8; jj++) s += VU[k][jj] * m[jj];
      P[k] = 0.5f * s + Sn[k * DD + d] * invrs[k];
    }
#pragma unroll
    for (int jj = 0; jj < 8; jj++) {
      float s = 0.f;
#pragma unroll
      for (int k = 0; k < 8; k++) s += Mi[jj][k] * P[k];
      Gn[jj * DD + d] = 0.5f * (0.5f * m[jj] + 0.25f * s);
    }
  }
}

// ---------------- RW: refined = 0.5*x + Z^T G; bf16 out + deferred row norms -----
__global__ __launch_bounds__(256) void k_rw_passC(
    const bf16* __restrict__ Xb, const float* __restrict__ z,
    const float* __restrict__ G, bf16* __restrict__ refb,
    float* __restrict__ invr) {
  int n = blockIdx.x, ch = blockIdx.y, tid = threadIdx.x;
  int lane = tid & 63, wid = tid >> 6;
  int d0 = tid * 8;
  int t0 = ch * 30;
  const float* Gn = G + (size_t)n * 8 * DD;
  float gr[8][8];
#pragma unroll
  for (int k = 0; k < 8; k++) {
    floatx4 a = *(const floatx4*)(Gn + k * DD + d0);
    floatx4 b = *(const floatx4*)(Gn + k * DD + d0 + 4);
    gr[k][0]=a.x; gr[k][1]=a.y; gr[k][2]=a.z; gr[k][3]=a.w;
    gr[k][4]=b.x; gr[k][5]=b.y; gr[k][6]=b.z; gr[k][7]=b.w;
  }
  __shared__ float red[30][4];
  const bf16* xrow = Xb + (size_t)n * TT * DD;
  for (int tt = 0; tt < 30; tt++) {
    int t = t0 + tt;
    float zt[8];
#pragma unroll
    for (int k = 0; k < 8; k++) zt[k] = z[((size_t)n * 8 + k) * TT + t];
    bf16x8 x8 = *(const bf16x8*)(xrow + (size_t)t * DD + d0);
    float r[8];
#pragma unroll
    for (int j = 0; j < 8; j++) {
      float s = 0.5f * (float)x8[j];
#pragma unroll
      for (int k = 0; k < 8; k++) s += zt[k] * gr[k][j];
      r[j] = s;
    }
    bf16x8 ro;
#pragma unroll
    for (int j = 0; j < 8; j++) ro[j] = (bf16)r[j];
    *(bf16x8*)(refb + (size_t)(n * TT + t) * DD + d0) = ro;
    float ss = 0.f;
#pragma unroll
    for (int j = 0; j < 8; j++) ss += r[j] * r[j];
    ss = wave_allreduce_sum(ss);
    if (lane == 0) red[tt][wid] = ss;
  }
  __syncthreads();
  if (tid < 30) {
    float tot = red[tid][0] + red[tid][1] + red[tid][2] + red[tid][3];
    invr[n * TT + t0 + tid] = 1.f / (sqrtf(tot) + 1e-9f);
  }
}

// ---------------- mu_pred: softmax_c(20 * nmu . nac) -----------------------------
__global__ void k_mu_pred(const float* __restrict__ nmu, const float* __restrict__ nacf,
                          float* __restrict__ outp) {
  int b = blockIdx.x;  // 0..127
  int tid = threadIdx.x, lane = tid & 63, wid = tid >> 6;
  const float* v = nmu + (size_t)b * DD;
  __shared__ float scr[21];
  for (int c = wid; c < 21; c += 4) {
    const float* a = nacf + (size_t)c * DD;
    float s = 0.f;
    for (int i = lane; i < DD; i += 64) s += v[i] * a[i];
    s = wave_allreduce_sum(s);
    if (lane == 0) scr[c] = s * 20.f;
  }
  __syncthreads();
  if (tid == 0) {
    float mx = scr[0];
    for (int c = 1; c < 21; c++) mx = fmaxf(mx, scr[c]);
    float se = 0.f;
    for (int c = 0; c < 21; c++) se += __expf(scr[c] - mx);
    float inv = 1.f / se;
    for (int c = 0; c < 21; c++) outp[(size_t)b * 21 + c] = __expf(scr[c] - mx) * inv;
  }
}

// ---------------- prediction pass1: 32-row MFMA tiles, async staging -------------
__global__ __launch_bounds__(256) void k_pred_p1(
    const bf16* __restrict__ Xb, const bf16* __restrict__ nacb,
    const float* __restrict__ invn,
    float* __restrict__ out_frm, float* __restrict__ out_att,
    float* __restrict__ natt, float* __restrict__ att_sums) {
  __shared__ bf16 As[32 * 64];
  __shared__ bf16 Bs[32 * 64];
  __shared__ float ssum[2][32];
  int tid = threadIdx.x, lane = tid & 63, wid = tid >> 6;
  int m0 = blockIdx.x * 32;
  if (tid < 64) ssum[tid >> 5][tid & 31] = 0.f;
  int lrow = lane & 15, lko = (lane >> 4) * 8;
  int r0 = (wid & 1) * 16, c0 = (wid >> 1) * 16;
  int crow = tid >> 3, cc8 = (tid & 7) * 8;
  const bf16* gA = Xb + (size_t)(m0 + crow) * DD + cc8;
  const bf16* gB = nacb + (size_t)crow * DD + cc8;
  bf16* lA = As + tid * 8;
  bf16* lB = Bs + tid * 8;
  floatx4 acc = {};
  for (int k0 = 0; k0 < DD; k0 += 64) {
    async_lds16(gA + k0, lA);
    async_lds16(gB + k0, lB);
    __syncthreads();
#pragma unroll
    for (int ks = 0; ks < 64; ks += 32) {
      bf16x8 a = *(const bf16x8*)(As + (r0 + lrow) * 64 + ks + lko);
      bf16x8 b = *(const bf16x8*)(Bs + (c0 + lrow) * 64 + ks + lko);
      acc = __builtin_amdgcn_mfma_f32_16x16x32_bf16(a, b, acc, 0, 0, 0);
    }
    __syncthreads();
  }
  int quad = lane >> 4;
  int nbase = m0 / TT;
  int c = c0 + lrow;
#pragma unroll
  for (int r = 0; r < 4; r++) {
    int row = m0 + r0 + quad * 4 + r;
    if (c < 22) {
      float s = acc[r] * invn[row] * 20.f;
      float sg = 1.f / (1.f + __expf(-s));
      int n_loc = row / TT - nbase;
      if (c < 21) out_frm[(size_t)row * 21 + c] = s;
      else out_att[row] = sg;
      natt[(size_t)row * 22 + c] = sg;
      atomicAdd(&ssum[n_loc][c], sg);
    }
  }
  __syncthreads();
  if (tid < 64) {
    int nl = tid >> 5, cs = tid & 31;
    int nn = nbase + nl;
    if (cs < 22 && nn < NB) {
      float v = ssum[nl][cs];
      if (v != 0.f) atomicAdd(&att_sums[nn * 22 + cs], v);
    }
  }
}

// ---------------- natt normalize -------------------------------------------------
__global__ void k_natt_norm(float* __restrict__ natt, const float* __restrict__ sums) {
  int idx = blockIdx.x * 256 + threadIdx.x;
  if (idx >= NT * 22) return;
  int row = idx / 22;
  int c = idx - row * 22;
  int n = row / TT;
  natt[idx] = natt[idx] / (sums[n * 22 + c] + 1e-5f);
}

// ---------------- prediction pass2: feats partials, one barrier per block --------
__global__ __launch_bounds__(256) void k_pred_p2(
    const bf16* __restrict__ Xb, const float* __restrict__ natt,
    float* __restrict__ partF) {  // [n][8][22][DD]
  int n = blockIdx.x, dh = blockIdx.y, tc = blockIdx.z, tid = threadIdx.x;
  int d = dh * 1024 + tid * 4;
  int t0 = tc * 94;
  int tcnt = min(94, TT - t0);
  __shared__ float sw[94 * 22];
  for (int i = tid; i < tcnt * 22; i += 256)
    sw[i] = natt[(size_t)(n * TT + t0) * 22 + i];
  __syncthreads();
  float ac[22][4] = {};
  const bf16* xrow = Xb + (size_t)n * TT * DD;
  for (int tt = 0; tt < tcnt; tt++) {
    int t = t0 + tt;
    bf16x4 x4 = *(const bf16x4*)(xrow + (size_t)t * DD + d);
    float xv[4] = {(float)x4[0], (float)x4[1], (float)x4[2], (float)x4[3]};
#pragma unroll
    for (int cidx = 0; cidx < 22; cidx++) {
      float w = sw[tt * 22 + cidx];
#pragma unroll
      for (int j = 0; j < 4; j++) ac[cidx][j] += w * xv[j];
    }
  }
  float* pb = partF + ((size_t)(n * 8 + tc) * 22) * DD + d;
#pragma unroll
  for (int cidx = 0; cidx < 22; cidx++) {
    floatx4 v = {ac[cidx][0], ac[cidx][1], ac[cidx][2], ac[cidx][3]};
    *(floatx4*)(pb + (size_t)cidx * DD) = v;
  }
}

// ---------------- reduce feats partials ------------------------------------------
__global__ void k_feat_finish(const float* __restrict__ partF, float* __restrict__ feats) {
  int idx = blockIdx.x * 256 + threadIdx.x;
  if (idx >= NB * 22 * DD) return;
  int n = idx / (22 * DD);
  int rem = idx - n * (22 * DD);
  const float* p = partF + ((size_t)n * 8) * (22 * DD) + rem;
  float s = 0.f;
#pragma unroll
  for (int tc = 0; tc < 8; tc++) s += p[(size_t)tc * 22 * DD];
  feats[idx] = s;
}

// ---------------- final scores + softmax -----------------------------------------
__global__ void k_pred_final(const float* __restrict__ feats, const float* __restrict__ nacf,
                             float* __restrict__ oca, float* __restrict__ ocw) {
  int n = blockIdx.x, tid = threadIdx.x, lane = tid & 63, wid = tid >> 6;
  const float* fn = feats + (size_t)n * 22 * DD;
  __shared__ float rnorm[22];
  __shared__ float scr[42];
  for (int r = wid; r < 22; r += 4) {
    const float* fv = fn + (size_t)r * DD;
    float s = 0.f;
    for (int i = lane; i < DD; i += 64) { float x = fv[i]; s += x * x; }
    s = wave_allreduce_sum(s);
    if (lane == 0) rnorm[r] = 1.f / (sqrtf(s) + 1e-9f);
  }
  __syncthreads();
  for (int idx = wid; idx < 42; idx += 4) {
    int c = (idx < 21) ? idx : (idx - 21);
    int fr = (idx < 21) ? c : 21;
    const float* fv = fn + (size_t)fr * DD;
    const float* av = nacf + (size_t)c * DD;
    float s = 0.f;
    for (int i = lane; i < DD; i += 64) s += fv[i] * av[i];
    s = wave_allreduce_sum(s);
    if (lane == 0) scr[idx] = s * 20.f * rnorm[fr];
  }
  __syncthreads();
  if (tid < 2) {
    int base = (tid == 0) ? 21 : 0;
    float* dst = ((tid == 0) ? oca : ocw) + (size_t)n * 21;
    float mx = scr[base];
    for (int c = 1; c < 21; c++) mx = fmaxf(mx, scr[base + c]);
    float se = 0.f;
    for (int c = 0; c < 21; c++) se += __expf(scr[base + c] - mx);
    float inv = 1.f / se;
    for (int c = 0; c < 21; c++) dst[c] = __expf(scr[base + c] - mx) * inv;
  }
}

extern "C" void kernel_launch(void* const* d_in, const int* in_sizes, int n_in,
                              void* d_out, int out_size, void* d_ws, size_t ws_size,
                              hipStream_t stream) {
  const float* x_in = (const float*)d_in[0];
  const float* W = (const float*)d_in[1];
  const float* bemb = (const float*)d_in[2];
  const float* mup = (const float*)d_in[3];
  const float* ac = (const float*)d_in[4];
  const float* fg = (const float*)d_in[5];
  float* out = (float*)d_out;

  char* ws = (char*)d_ws;
  bf16* Wt = (bf16*)ws;                       // 8,388,608
  bf16* Xb = (bf16*)(ws + 8388608);           // 49,283,072 (12032 rows)
  bf16* Rb = (bf16*)(ws + 57671680);          // 49,283,072
  bf16* Ab = (bf16*)(ws + 106954752);         // 49,283,072 (shared: Ab -> partial/partF)
  float* partial = (float*)(ws + 106954752);
  float* partF = (float*)(ws + 106954752);
  bf16* nacb = (bf16*)(ws + 156237824);       // 131,072
  float* f = (float*)(ws + 156368896);
  float* nacf = f;                 // 45,056
  float* mu = nacf + 45056;        // 262,144
  float* nmu = mu + 262144;        // 262,144
  float* accS = nmu + 262144;      // 262,144
  float* G = accS + 262144;        // 262,144
  float* z = G + 262144;           // 96,000
  float* natt = z + 96000;         // 264,000
  float* feats = natt + 264000;    // 720,896
  float* invx = feats + 720896;    // 12,032
  float* invr = invx + 12032;      // 12,032
  // zeroed region (single memset): rowsum[6][128] | asums_o[352] | asums_m[352] | rowsq[12032]
  float* rowsum = invr + 12032;    // 768
  float* asums_o = rowsum + 768;   // 352
  float* asums_m = asums_o + 352;  // 352
  float* rowsq = asums_m + 352;    // 12,032

  float* o_ca = out;
  float* o_cw = out + 336;
  float* o_att = out + 672;
  float* o_frm = out + 12672;
  float* m_ca = out + 264672;
  float* m_cw = out + 265008;
  float* m_att = out + 265344;
  float* m_frm = out + 277344;
  float* x_out = out + 529344;
  float* mu_out = out + 25105344;
  float* mup_out = out + 25367488;

  hipMemsetAsync(rowsum, 0, (768 + 352 + 352 + 12032) * sizeof(float), stream);
  k_prep_w<<<dim3(64, 64), dim3(32, 8), 0, stream>>>(W, Wt);
  k_ac_norm<<<32, 256, 0, stream>>>(ac, fg, nacf, nacb);
  k_xbf16<<<12032, 256, 0, stream>>>(x_in, Ab);
  k_gemm<<<dim3(16, 94), 256, 0, stream>>>(Ab, Wt, bemb, x_out, Xb, rowsq);
  k_invx<<<47, 256, 0, stream>>>(rowsq, invx);
  k_mu_norm0<<<128, 256, 0, stream>>>(mup, nmu);
  for (int it = 0; it < 5; it++) {
    bool last = (it == 4);
    k_em_pass<<<dim3(16, 32), 512, 0, stream>>>(Xb, nmu, invx, partial,
                                                rowsum + it * 128, nullptr);
    k_mu_finish<<<128, 256, 0, stream>>>(partial, last ? (rowsum + 4 * 128) : nullptr,
                                         nullptr, last ? mu : nullptr,
                                         last ? mu_out : nullptr, nmu);
  }
  k_em_pass<<<dim3(16, 32), 512, 0, stream>>>(Xb, nmu, invx, partial, rowsum + 5 * 128, z);
  k_mu_finish<<<128, 256, 0, stream>>>(partial, nullptr, accS, nullptr, nullptr, nullptr);
  k_woodbury<<<16, 256, 0, stream>>>(z, rowsum + 5 * 128, accS, mu, G);
  k_mu_pred<<<128, 256, 0, stream>>>(nmu, nacf, mup_out);
  k_rw_passC<<<dim3(16, 25), 256, 0, stream>>>(Xb, z, G, Rb, invr);
  // o-phase (on x)
  k_pred_p1<<<375, 256, 0, stream>>>(Xb, nacb, invx, o_frm, o_att, natt, asums_o);
  k_natt_norm<<<1032, 256, 0, stream>>>(natt, asums_o);
  k_pred_p2<<<dim3(16, 2, 8), 256, 0, stream>>>(Xb, natt, partF);
  k_feat_finish<<<2816, 256, 0, stream>>>(partF, feats);
  k_pred_final<<<16, 256, 0, stream>>>(feats, nacf, o_ca, o_cw);
  // m-phase (on refined)
  k_pred_p1<<<375, 256, 0, stream>>>(Rb, nacb, invr, m_frm, m_att, natt, asums_m);
  k_natt_norm<<<1032, 256, 0, stream>>>(natt, asums_m);
  k_pred_p2<<<dim3(16, 2, 8), 256, 0, stream>>>(Rb, natt, partF);
  k_feat_finish<<<2816, 256, 0, stream>>>(partF, feats);
  k_pred_final<<<16, 256, 0, stream>>>(feats, nacf, m_ca, m_cw);
}

// Round 3
// 1192.361 us; speedup vs baseline: 1.4395x; 1.1515x over previous
//
#include <hip/hip_runtime.h>

#define NB 16
#define TT 750
#define DD 2048
#define KK 8
#define CC 21
#define NT 12000

typedef __bf16 bf16;
typedef __attribute__((ext_vector_type(4))) float floatx4;
typedef __attribute__((ext_vector_type(8))) __bf16 bf16x8;
typedef __attribute__((ext_vector_type(4))) __bf16 bf16x4;

__device__ __forceinline__ float wave_allreduce_sum(float v) {
#pragma unroll
  for (int m = 32; m > 0; m >>= 1) v += __shfl_xor(v, m, 64);
  return v;
}

__device__ __forceinline__ void async_lds16(const bf16* g, bf16* l) {
  __builtin_amdgcn_global_load_lds(
      (const __attribute__((address_space(1))) void*)(g),
      (__attribute__((address_space(3))) void*)(l), 16, 0, 0);
}

// ============ fused prep: W transpose+bf16 | ac_norm | mu_norm0 | x->bf16 =======
// grid: [0,4096) prep_w | [4096,4128) ac_norm | [4128,4256) mu_norm0 | [4256,7264) xbf16
__global__ __launch_bounds__(256) void k_prep(
    const float* __restrict__ W, bf16* __restrict__ Wt,
    const float* __restrict__ ac, const float* __restrict__ fg,
    float* __restrict__ nacf, bf16* __restrict__ nacb,
    const float* __restrict__ mup, float* __restrict__ nmu,
    const float* __restrict__ x, bf16* __restrict__ Ab) {
  int b = blockIdx.x, tid = threadIdx.x;
  __shared__ float tile[32][33];
  __shared__ float sb[4];
  if (b < 4096) {  // ---- W transpose + bf16
    int j0 = (b & 63) * 32, k0 = (b >> 6) * 32;
    int tx = tid & 31, ty = tid >> 5;
#pragma unroll
    for (int i = 0; i < 4; i++)
      tile[ty + 8 * i][tx] = W[(size_t)(k0 + ty + 8 * i) * DD + j0 + tx];
    __syncthreads();
#pragma unroll
    for (int i = 0; i < 4; i++)
      Wt[(size_t)(j0 + ty + 8 * i) * DD + k0 + tx] = (bf16)tile[tx][ty + 8 * i];
    return;
  }
  if (b < 4128) {  // ---- ac_center (+fg row 21) normalize, rows 22..31 zero
    int r = b - 4096;
    int d0 = tid * 8;
    if (r >= 22) {
#pragma unroll
      for (int j = 0; j < 8; j++) nacb[(size_t)r * DD + d0 + j] = (bf16)0.f;
      return;
    }
    const float* src = (r < 21) ? (ac + (size_t)r * DD) : fg;
    float v[8];
    floatx4 a = *(const floatx4*)(src + d0);
    floatx4 c = *(const floatx4*)(src + d0 + 4);
    v[0]=a.x; v[1]=a.y; v[2]=a.z; v[3]=a.w; v[4]=c.x; v[5]=c.y; v[6]=c.z; v[7]=c.w;
    float ss = 0.f;
#pragma unroll
    for (int j = 0; j < 8; j++) ss += v[j] * v[j];
    ss = wave_allreduce_sum(ss);
    int lane = tid & 63, wid = tid >> 6;
    if (lane == 0) sb[wid] = ss;
    __syncthreads();
    float inv = 1.f / (sqrtf(sb[0] + sb[1] + sb[2] + sb[3]) + 1e-9f);
#pragma unroll
    for (int j = 0; j < 8; j++) {
      float nv = v[j] * inv;
      nacf[(size_t)r * DD + d0 + j] = nv;
      nacb[(size_t)r * DD + d0 + j] = (bf16)nv;
    }
    return;
  }
  if (b < 4256) {  // ---- nmu iter-0 = l2n(mu_param[k]) per (n,k)
    int bb = b - 4128;  // n*8+k
    int k = bb & 7;
    int lane = tid & 63, wid = tid >> 6;
    const float* p = mup + (size_t)k * DD + tid * 8;
    float v[8];
    floatx4 a = *(const floatx4*)p;
    floatx4 c = *(const floatx4*)(p + 4);
    v[0]=a.x; v[1]=a.y; v[2]=a.z; v[3]=a.w; v[4]=c.x; v[5]=c.y; v[6]=c.z; v[7]=c.w;
    float ss = 0.f;
#pragma unroll
    for (int j = 0; j < 8; j++) ss += v[j] * v[j];
    ss = wave_allreduce_sum(ss);
    if (lane == 0) sb[wid] = ss;
    __syncthreads();
    float inv = 1.f / (sqrtf(sb[0] + sb[1] + sb[2] + sb[3]) + 1e-9f);
    float* q = nmu + (size_t)bb * DD + tid * 8;
#pragma unroll
    for (int j = 0; j < 8; j++) q[j] = v[j] * inv;
    return;
  }
  // ---- x -> bf16 (rows >= NT zero), 4 row-units per block
  int unit0 = (b - 4256) * 4;
#pragma unroll
  for (int u = 0; u < 4; u++) {
    size_t base = ((size_t)(unit0 + u) * 256 + tid) * 8;
    int row = (int)(base >> 11);
    bf16x8 o = {};
    if (row < NT) {
      floatx4 a = *(const floatx4*)(x + base);
      floatx4 c = *(const floatx4*)(x + base + 4);
      o[0]=(bf16)a.x; o[1]=(bf16)a.y; o[2]=(bf16)a.z; o[3]=(bf16)a.w;
      o[4]=(bf16)c.x; o[5]=(bf16)c.y; o[6]=(bf16)c.z; o[7]=(bf16)c.w;
    }
    *(bf16x8*)(Ab + base) = o;
  }
}

// ============ embedding GEMM: XOR-swizzled LDS, XCD-aware remap, fused rowsq ====
__global__ __launch_bounds__(256) void k_gemm(
    const bf16* __restrict__ Ab, const bf16* __restrict__ Bt,
    const float* __restrict__ bias,
    float* __restrict__ Cout, bf16* __restrict__ Cb, float* __restrict__ rowsq) {
  __shared__ bf16 As[128 * 64];
  __shared__ bf16 Bs[128 * 64];
  int tid = threadIdx.x;
  int bid = blockIdx.x;            // 1504 = 8 XCD * (2 nstrips * 94 m)
  int xcd = bid & 7;
  int j = bid >> 3;                // 0..187
  int n0 = (xcd * 2 + (j >= 94 ? 1 : 0)) * 128;
  int m0 = (j % 94) * 128;
  int wid = tid >> 6, lane = tid & 63;
  int wm = (wid >> 1) * 64, wn = (wid & 1) * 64;
  int lrow = lane & 15, lko = (lane >> 4) * 8;
  int lr7 = lrow & 7;
  floatx4 acc[4][4] = {};
  int crow = tid >> 3;
  int jg = ((tid & 7) ^ (crow & 7)) * 8;   // XOR swizzle on global column chunk
  const bf16* gA = Ab + (size_t)(m0 + crow) * DD + jg;
  const bf16* gB = Bt + (size_t)(n0 + crow) * DD + jg;
  bf16* lA = As + tid * 8;
  bf16* lB = Bs + tid * 8;
  for (int k0 = 0; k0 < DD; k0 += 64) {
#pragma unroll
    for (int s = 0; s < 4; s++)
      async_lds16(gA + (size_t)(32 * s) * DD + k0, lA + 2048 * s);
#pragma unroll
    for (int s = 0; s < 4; s++)
      async_lds16(gB + (size_t)(32 * s) * DD + k0, lB + 2048 * s);
    __syncthreads();
#pragma unroll
    for (int ks = 0; ks < 64; ks += 32) {
      bf16x8 af[4], bfr[4];
#pragma unroll
      for (int i = 0; i < 4; i++) {
        int sw = (((ks + lko) >> 3) ^ lr7) * 8;
        af[i] = *(const bf16x8*)(As + (wm + i * 16 + lrow) * 64 + sw);
      }
#pragma unroll
      for (int jj = 0; jj < 4; jj++) {
        int sw = (((ks + lko) >> 3) ^ lr7) * 8;
        bfr[jj] = *(const bf16x8*)(Bs + (wn + jj * 16 + lrow) * 64 + sw);
      }
#pragma unroll
      for (int i = 0; i < 4; i++)
#pragma unroll
        for (int jj = 0; jj < 4; jj++)
          acc[i][jj] = __builtin_amdgcn_mfma_f32_16x16x32_bf16(af[i], bfr[jj], acc[i][jj], 0, 0, 0);
    }
    __syncthreads();
  }
  int quad = lane >> 4;
  float bv[4];
#pragma unroll
  for (int jj = 0; jj < 4; jj++) bv[jj] = bias[n0 + wn + jj * 16 + lrow];
#pragma unroll
  for (int i = 0; i < 4; i++) {
#pragma unroll
    for (int r = 0; r < 4; r++) {
      int row = m0 + wm + i * 16 + quad * 4 + r;
      bool ok = (row < NT);
      float sq = 0.f;
#pragma unroll
      for (int jj = 0; jj < 4; jj++) {
        int col = n0 + wn + jj * 16 + lrow;
        float v = acc[i][jj][r] + bv[jj];
        v = fmaxf(v, 0.f);
        if (ok) {
          Cout[(size_t)row * DD + col] = v;
          Cb[(size_t)row * DD + col] = (bf16)v;
        }
        sq += v * v;
      }
#pragma unroll
      for (int m = 1; m < 16; m <<= 1) sq += __shfl_xor(sq, m, 64);
      if (ok && lrow == 0) atomicAdd(&rowsq[row], sq);
    }
  }
}

// ============ EM streaming pass: wave-per-cluster, prefetched t-loop ============
__global__ __launch_bounds__(512) void k_em_pass(
    const bf16* __restrict__ Xb, const float* __restrict__ nmu,
    const float* __restrict__ rowsq,
    float* __restrict__ partial,   // [n][32][8][DD]
    float* __restrict__ rowsum,    // [n][8] (atomic, pre-zeroed)
    float* __restrict__ zout) {    // optional [n][8][TT]
  int n = blockIdx.x, ch = blockIdx.y, tid = threadIdx.x;
  int lane = tid & 63, w = tid >> 6;  // w = cluster
  __shared__ uint32_t xs[1024];
  __shared__ float red[8];
  const float* nm = nmu + (size_t)(n * 8 + w) * DD;
  float mur[32];
#pragma unroll
  for (int j = 0; j < 16; j++) {
    float2 mv = *(const float2*)(nm + 2 * lane + 128 * j);
    mur[2 * j] = mv.x; mur[2 * j + 1] = mv.y;
  }
  float ar[32] = {};
  float rs = 0.f;
  const bf16* xrow = Xb + (size_t)n * TT * DD;
  int t0 = ch * 24;
  int cnt = min(24, TT - t0);
  uint2 g = *(const uint2*)(xrow + (size_t)t0 * DD + tid * 4);
  for (int tt = 0; tt < cnt; tt++) {
    int t = t0 + tt;
    *(uint2*)&xs[tid * 2] = g;
    __syncthreads();
    if (tt + 1 < cnt) g = *(const uint2*)(xrow + (size_t)(t + 1) * DD + tid * 4);
    float xv[32];
    float p = 0.f;
#pragma unroll
    for (int j = 0; j < 16; j++) {
      uint32_t u = xs[lane + 64 * j];
      float lo = __uint_as_float(u << 16);
      float hi = __uint_as_float(u & 0xffff0000u);
      xv[2 * j] = lo; xv[2 * j + 1] = hi;
      p += mur[2 * j] * lo + mur[2 * j + 1] * hi;
    }
    p = wave_allreduce_sum(p);
    if (lane == 0) red[w] = p;
    __syncthreads();
    float sc = 5.f / (sqrtf(rowsq[n * TT + t]) + 1e-9f);
    float s[8];
#pragma unroll
    for (int k = 0; k < 8; k++) s[k] = red[k] * sc;
    float mx = s[0];
#pragma unroll
    for (int k = 1; k < 8; k++) mx = fmaxf(mx, s[k]);
    float se = 0.f;
#pragma unroll
    for (int k = 0; k < 8; k++) se += __expf(s[k] - mx);
    float z = __expf(s[w] - mx) / se;
    rs += z;
#pragma unroll
    for (int i = 0; i < 32; i++) ar[i] += z * xv[i];
    if (zout != nullptr && lane == 0) zout[(size_t)(n * 8 + w) * TT + t] = z;
  }
  float* pb = partial + ((size_t)(n * 32 + ch) * 8 + w) * DD;
#pragma unroll
  for (int j = 0; j < 16; j++) {
    float2 v = {ar[2 * j], ar[2 * j + 1]};
    *(float2*)(pb + 2 * lane + 128 * j) = v;
  }
  if (lane == 0) atomicAdd(&rowsum[n * 8 + w], rs);
}

// ============ reduce chunk partials + optional divide + fused l2-norm ===========
__global__ void k_mu_finish(const float* __restrict__ partial, const float* __restrict__ rs,
                            float* __restrict__ raw_out, float* __restrict__ mu_ws,
                            float* __restrict__ mu_out, float* __restrict__ nmu_out) {
  int b = blockIdx.x;  // n*8+k
  int n = b >> 3, k = b & 7;
  int tid = threadIdx.x, lane = tid & 63, wid = tid >> 6;
  int d0 = tid * 8;
  const float* p = partial + ((size_t)n * 32 * 8 + k) * DD + d0;
  float s[8] = {};
  for (int ch = 0; ch < 32; ch++) {
    floatx4 a = *(const floatx4*)(p + (size_t)ch * 8 * DD);
    floatx4 c = *(const floatx4*)(p + (size_t)ch * 8 * DD + 4);
    s[0]+=a.x; s[1]+=a.y; s[2]+=a.z; s[3]+=a.w; s[4]+=c.x; s[5]+=c.y; s[6]+=c.z; s[7]+=c.w;
  }
  float m[8];
  float invr = (rs != nullptr) ? 1.f / (rs[b] + 1e-9f) : 1.f;
#pragma unroll
  for (int j = 0; j < 8; j++) m[j] = s[j] * invr;
  if (raw_out != nullptr) {
#pragma unroll
    for (int j = 0; j < 8; j++) raw_out[(size_t)b * DD + d0 + j] = s[j];
  }
  if (mu_ws != nullptr) {
#pragma unroll
    for (int j = 0; j < 8; j++) {
      mu_ws[(size_t)b * DD + d0 + j] = m[j];
      mu_out[(size_t)b * DD + d0 + j] = m[j];
    }
  }
  if (nmu_out != nullptr) {
    float ss = 0.f;
#pragma unroll
    for (int j = 0; j < 8; j++) ss += m[j] * m[j];
    ss = wave_allreduce_sum(ss);
    __shared__ float sb[4];
    if (lane == 0) sb[wid] = ss;
    __syncthreads();
    float inv = 1.f / (sqrtf(sb[0] + sb[1] + sb[2] + sb[3]) + 1e-9f);
#pragma unroll
    for (int j = 0; j < 8; j++) nmu_out[(size_t)b * DD + d0 + j] = m[j] * inv;
  }
}

// ============ Woodbury (blocks 0..15) + mu_pred (blocks 16..143) ================
__global__ void k_wood_mupred(const float* __restrict__ z, const float* __restrict__ rowsum,
                              const float* __restrict__ S, const float* __restrict__ mu,
                              float* __restrict__ G,
                              const float* __restrict__ nmu, const float* __restrict__ nacf,
                              float* __restrict__ mupred) {
  int tid = threadIdx.x;
  if (blockIdx.x >= 16) {  // ---- mu_pred
    int b = blockIdx.x - 16;  // 0..127
    int lane = tid & 63, wid = tid >> 6;
    const float* v = nmu + (size_t)b * DD;
    __shared__ float scr[21];
    for (int c = wid; c < 21; c += 4) {
      const float* a = nacf + (size_t)c * DD;
      float s = 0.f;
      for (int i = lane * 4; i < DD; i += 256) {
        floatx4 vv = *(const floatx4*)(v + i);
        floatx4 aa = *(const floatx4*)(a + i);
        s += vv.x * aa.x + vv.y * aa.y + vv.z * aa.z + vv.w * aa.w;
      }
      s = wave_allreduce_sum(s);
      if (lane == 0) scr[c] = s * 20.f;
    }
    __syncthreads();
    if (tid == 0) {
      float mx = scr[0];
      for (int c = 1; c < 21; c++) mx = fmaxf(mx, scr[c]);
      float se = 0.f;
      for (int c = 0; c < 21; c++) se += __expf(scr[c] - mx);
      float inv = 1.f / se;
      for (int c = 0; c < 21; c++) mupred[(size_t)b * 21 + c] = __expf(scr[c] - mx) * inv;
    }
    return;
  }
  // ---- Woodbury
  int n = blockIdx.x;
  __shared__ float VU[8][8];
  __shared__ float Mi[8][8];
  __shared__ float invrs[8];
  __shared__ float vus[64][4];
  if (tid < 8) invrs[tid] = 1.f / (rowsum[n * 8 + tid] + 1e-9f);
  {
    int pr = tid >> 2, sl = tid & 3;
    const float* zj = z + ((size_t)n * 8 + (pr >> 3)) * TT;
    const float* zk = z + ((size_t)n * 8 + (pr & 7)) * TT;
    float s = 0.f;
    for (int t = sl; t < TT; t += 4) s += zj[t] * zk[t];
    vus[pr][sl] = s;
  }
  __syncthreads();
  if (tid < 64)
    VU[tid >> 3][tid & 7] =
        (vus[tid][0] + vus[tid][1] + vus[tid][2] + vus[tid][3]) * invrs[tid >> 3];
  __syncthreads();
  if (tid == 0) {
    float M[8][16];
    for (int i = 0; i < 8; i++)
      for (int jj = 0; jj < 8; jj++) {
        M[i][jj] = ((i == jj) ? 1.f : 0.f) - 0.25f * VU[i][jj];
        M[i][8 + jj] = (i == jj) ? 1.f : 0.f;
      }
    for (int c = 0; c < 8; c++) {
      float pv = 1.f / M[c][c];
      for (int jj = 0; jj < 16; jj++) M[c][jj] *= pv;
      for (int rr = 0; rr < 8; rr++)
        if (rr != c) {
          float f = M[rr][c];
          for (int jj = 0; jj < 16; jj++) M[rr][jj] -= f * M[c][jj];
        }
    }
    for (int i = 0; i < 8; i++)
      for (int jj = 0; jj < 8; jj++) Mi[i][jj] = M[i][8 + jj];
  }
  __syncthreads();
  const float* mun = mu + (size_t)n * 8 * DD;
  const float* Sn = S + (size_t)n * 8 * DD;
  float* Gn = G + (size_t)n * 8 * DD;
  for (int d = tid; d < DD; d += 256) {
    float m[8], P[8];
#pragma unroll
    for (int k = 0; k < 8; k++) m[k] = mun[k * DD + d];
#pragma unroll
    for (int k = 0; k < 8; k++) {
      float s = 0.f;
#pragma unroll
      for (int jj = 0; jj < 8; jj++) s += VU[k][jj] * m[jj];
      P[k] = 0.5f * s + Sn[k * DD + d] * invrs[k];
    }
#pragma unroll
    for (int jj = 0; jj < 8; jj++) {
      float s = 0.f;
#pragma unroll
      for (int k = 0; k < 8; k++) s += Mi[jj][k] * P[k];
      Gn[jj * DD + d] = 0.5f * (0.5f * m[jj] + 0.25f * s);
    }
  }
}

// ============ RW: refined = 0.5*x + Z^T G; prefetched; deferred norms ===========
__global__ __launch_bounds__(256) void k_rw_passC(
    const bf16* __restrict__ Xb, const float* __restrict__ z,
    const float* __restrict__ G, bf16* __restrict__ refb,
    float* __restrict__ invr) {
  int n = blockIdx.x, ch = blockIdx.y, tid = threadIdx.x;
  int lane = tid & 63, wid = tid >> 6;
  int d0 = tid * 8;
  int t0 = ch * 30;
  const float* Gn = G + (size_t)n * 8 * DD;
  float gr[8][8];
#pragma unroll
  for (int k = 0; k < 8; k++) {
    floatx4 a = *(const floatx4*)(Gn + k * DD + d0);
    floatx4 b = *(const floatx4*)(Gn + k * DD + d0 + 4);
    gr[k][0]=a.x; gr[k][1]=a.y; gr[k][2]=a.z; gr[k][3]=a.w;
    gr[k][4]=b.x; gr[k][5]=b.y; gr[k][6]=b.z; gr[k][7]=b.w;
  }
  __shared__ float red[30][4];
  const bf16* xrow = Xb + (size_t)n * TT * DD;
  bf16x8 xg = *(const bf16x8*)(xrow + (size_t)t0 * DD + d0);
  for (int tt = 0; tt < 30; tt++) {
    int t = t0 + tt;
    bf16x8 x8 = xg;
    if (tt + 1 < 30) xg = *(const bf16x8*)(xrow + (size_t)(t + 1) * DD + d0);
    float zt[8];
#pragma unroll
    for (int k = 0; k < 8; k++) zt[k] = z[((size_t)n * 8 + k) * TT + t];
    float r[8];
#pragma unroll
    for (int j = 0; j < 8; j++) {
      float s = 0.5f * (float)x8[j];
#pragma unroll
      for (int k = 0; k < 8; k++) s += zt[k] * gr[k][j];
      r[j] = s;
    }
    bf16x8 ro;
#pragma unroll
    for (int j = 0; j < 8; j++) ro[j] = (bf16)r[j];
    *(bf16x8*)(refb + (size_t)(n * TT + t) * DD + d0) = ro;
    float ss = 0.f;
#pragma unroll
    for (int j = 0; j < 8; j++) ss += r[j] * r[j];
    ss = wave_allreduce_sum(ss);
    if (lane == 0) red[tt][wid] = ss;
  }
  __syncthreads();
  if (tid < 30) {
    float tot = red[tid][0] + red[tid][1] + red[tid][2] + red[tid][3];
    invr[n * TT + t0 + tid] = 1.f / (sqrtf(tot) + 1e-9f);
  }
}

// ============ pred pass1: 32-row MFMA tiles, dbuf LDS, swizzled =================
// mode 0: invn = 1/(norm+eps) array.  mode 1: invn = rowsq (take rsqrt inline)
__global__ __launch_bounds__(256) void k_pred_p1(
    const bf16* __restrict__ Xb, const bf16* __restrict__ nacb,
    const float* __restrict__ invn, int mode,
    float* __restrict__ out_frm, float* __restrict__ out_att,
    float* __restrict__ natt, float* __restrict__ att_sums) {
  __shared__ bf16 As[2][2048];
  __shared__ bf16 Bs[2][2048];
  __shared__ float ssum[2][32];
  int tid = threadIdx.x, lane = tid & 63, wid = tid >> 6;
  int m0 = blockIdx.x * 32;
  if (tid < 64) ssum[tid >> 5][tid & 31] = 0.f;
  int lrow = lane & 15, lko = (lane >> 4) * 8;
  int lr7 = lrow & 7;
  int r0 = (wid & 1) * 16, c0 = (wid >> 1) * 16;
  int crow = tid >> 3;
  int jg = ((tid & 7) ^ (crow & 7)) * 8;
  const bf16* gA = Xb + (size_t)(m0 + crow) * DD + jg;
  const bf16* gB = nacb + (size_t)crow * DD + jg;
  async_lds16(gA, &As[0][tid * 8]);
  async_lds16(gB, &Bs[0][tid * 8]);
  floatx4 acc = {};
  int buf = 0;
  for (int k0 = 0; k0 < DD; k0 += 64) {
    __syncthreads();
    if (k0 + 64 < DD) {
      async_lds16(gA + k0 + 64, &As[buf ^ 1][tid * 8]);
      async_lds16(gB + k0 + 64, &Bs[buf ^ 1][tid * 8]);
    }
#pragma unroll
    for (int ks = 0; ks < 64; ks += 32) {
      int sw = ((((ks + lko) >> 3) ^ lr7)) * 8;
      bf16x8 a = *(const bf16x8*)(&As[buf][(r0 + lrow) * 64 + sw]);
      bf16x8 b = *(const bf16x8*)(&Bs[buf][(c0 + lrow) * 64 + sw]);
      acc = __builtin_amdgcn_mfma_f32_16x16x32_bf16(a, b, acc, 0, 0, 0);
    }
    buf ^= 1;
  }
  __syncthreads();
  int quad = lane >> 4;
  int nbase = m0 / TT;
  int c = c0 + lrow;
#pragma unroll
  for (int r = 0; r < 4; r++) {
    int row = m0 + r0 + quad * 4 + r;
    if (c < 22) {
      float iv = mode ? (1.f / (sqrtf(invn[row]) + 1e-9f)) : invn[row];
      float s = acc[r] * iv * 20.f;
      float sg = 1.f / (1.f + __expf(-s));
      int n_loc = row / TT - nbase;
      if (c < 21) out_frm[(size_t)row * 21 + c] = s;
      else out_att[row] = sg;
      natt[(size_t)row * 22 + c] = sg;
      atomicAdd(&ssum[n_loc][c], sg);
    }
  }
  __syncthreads();
  if (tid < 64) {
    int nl = tid >> 5, cs = tid & 31;
    int nn = nbase + nl;
    if (cs < 22 && nn < NB) {
      float v = ssum[nl][cs];
      if (v != 0.f) atomicAdd(&att_sums[nn * 22 + cs], v);
    }
  }
}

// ============ pred pass2: fused natt-normalize + prefetch, register acc =========
__global__ __launch_bounds__(256) void k_pred_p2(
    const bf16* __restrict__ Xb, const float* __restrict__ natt,
    const float* __restrict__ sums, float* __restrict__ partF) {  // [n][8][22][DD]
  int n = blockIdx.x, dh = blockIdx.y, tc = blockIdx.z, tid = threadIdx.x;
  int d = dh * 1024 + tid * 4;
  int t0 = tc * 94;
  int tcnt = min(94, TT - t0);
  __shared__ float sw[94 * 22];
  for (int i = tid; i < tcnt * 22; i += 256) {
    int c = i - (i / 22) * 22;
    sw[i] = natt[(size_t)(n * TT + t0) * 22 + i] / (sums[n * 22 + c] + 1e-5f);
  }
  __syncthreads();
  float ac[22][4] = {};
  const bf16* xrow = Xb + (size_t)n * TT * DD;
  bf16x4 xg = *(const bf16x4*)(xrow + (size_t)t0 * DD + d);
  for (int tt = 0; tt < tcnt; tt++) {
    bf16x4 x4 = xg;
    if (tt + 1 < tcnt) xg = *(const bf16x4*)(xrow + (size_t)(t0 + tt + 1) * DD + d);
    float xv[4] = {(float)x4[0], (float)x4[1], (float)x4[2], (float)x4[3]};
#pragma unroll
    for (int cidx = 0; cidx < 22; cidx++) {
      float w = sw[tt * 22 + cidx];
#pragma unroll
      for (int jj = 0; jj < 4; jj++) ac[cidx][jj] += w * xv[jj];
    }
  }
  float* pb = partF + ((size_t)(n * 8 + tc) * 22) * DD + d;
#pragma unroll
  for (int cidx = 0; cidx < 22; cidx++) {
    floatx4 v = {ac[cidx][0], ac[cidx][1], ac[cidx][2], ac[cidx][3]};
    *(floatx4*)(pb + (size_t)cidx * DD) = v;
  }
}

// ============ reduce feats partials =============================================
__global__ void k_feat_finish(const float* __restrict__ partF, float* __restrict__ feats) {
  int idx = blockIdx.x * 256 + threadIdx.x;
  if (idx >= NB * 22 * DD) return;
  int n = idx / (22 * DD);
  int rem = idx - n * (22 * DD);
  const float* p = partF + ((size_t)n * 8) * (22 * DD) + rem;
  float s = 0.f;
#pragma unroll
  for (int tc = 0; tc < 8; tc++) s += p[(size_t)tc * 22 * DD];
  feats[idx] = s;
}

// ============ final scores + softmax ============================================
__global__ void k_pred_final(const float* __restrict__ feats, const float* __restrict__ nacf,
                             float* __restrict__ oca, float* __restrict__ ocw) {
  int n = blockIdx.x, tid = threadIdx.x, lane = tid & 63, wid = tid >> 6;
  const float* fn = feats + (size_t)n * 22 * DD;
  __shared__ float rnorm[22];
  __shared__ float scr[42];
  for (int r = wid; r < 22; r += 4) {
    const float* fv = fn + (size_t)r * DD;
    float s = 0.f;
    for (int i = lane * 4; i < DD; i += 256) {
      floatx4 v = *(const floatx4*)(fv + i);
      s += v.x * v.x + v.y * v.y + v.z * v.z + v.w * v.w;
    }
    s = wave_allreduce_sum(s);
    if (lane == 0) rnorm[r] = 1.f / (sqrtf(s) + 1e-9f);
  }
  __syncthreads();
  for (int idx = wid; idx < 42; idx += 4) {
    int c = (idx < 21) ? idx : (idx - 21);
    int fr = (idx < 21) ? c : 21;
    const float* fv = fn + (size_t)fr * DD;
    const float* av = nacf + (size_t)c * DD;
    float s = 0.f;
    for (int i = lane * 4; i < DD; i += 256) {
      floatx4 v = *(const floatx4*)(fv + i);
      floatx4 a = *(const floatx4*)(av + i);
      s += v.x * a.x + v.y * a.y + v.z * a.z + v.w * a.w;
    }
    s = wave_allreduce_sum(s);
    if (lane == 0) scr[idx] = s * 20.f * rnorm[fr];
  }
  __syncthreads();
  if (tid < 2) {
    int base = (tid == 0) ? 21 : 0;
    float* dst = ((tid == 0) ? oca : ocw) + (size_t)n * 21;
    float mx = scr[base];
    for (int c = 1; c < 21; c++) mx = fmaxf(mx, scr[base + c]);
    float se = 0.f;
    for (int c = 0; c < 21; c++) se += __expf(scr[base + c] - mx);
    float inv = 1.f / se;
    for (int c = 0; c < 21; c++) dst[c] = __expf(scr[base + c] - mx) * inv;
  }
}

extern "C" void kernel_launch(void* const* d_in, const int* in_sizes, int n_in,
                              void* d_out, int out_size, void* d_ws, size_t ws_size,
                              hipStream_t stream) {
  const float* x_in = (const float*)d_in[0];
  const float* W = (const float*)d_in[1];
  const float* bemb = (const float*)d_in[2];
  const float* mup = (const float*)d_in[3];
  const float* ac = (const float*)d_in[4];
  const float* fg = (const float*)d_in[5];
  float* out = (float*)d_out;

  char* ws = (char*)d_ws;
  bf16* Wt = (bf16*)ws;                       // 8,388,608
  bf16* Xb = (bf16*)(ws + 8388608);           // 49,283,072 (12032 rows)
  bf16* Rb = (bf16*)(ws + 57671680);          // 49,283,072
  bf16* Ab = (bf16*)(ws + 106954752);         // 49,283,072 (shared: Ab -> partial/partF)
  float* partial = (float*)(ws + 106954752);
  float* partF = (float*)(ws + 106954752);
  bf16* nacb = (bf16*)(ws + 156237824);       // 131,072
  float* f = (float*)(ws + 156368896);
  float* nacf = f;                 // 45,056
  float* mu = nacf + 45056;        // 262,144
  float* nmu = mu + 262144;        // 262,144
  float* accS = nmu + 262144;      // 262,144
  float* G = accS + 262144;        // 262,144
  float* z = G + 262144;           // 96,000
  float* natt = z + 96000;         // 264,000
  float* feats = natt + 264000;    // 720,896
  float* invr = feats + 720896;    // 12,032
  // zeroed region (single memset): rowsum[6][128] | asums_o[352] | asums_m[352] | rowsq[12032]
  float* rowsum = invr + 12032;    // 768
  float* asums_o = rowsum + 768;   // 352
  float* asums_m = asums_o + 352;  // 352
  float* rowsq = asums_m + 352;    // 12,032

  float* o_ca = out;
  float* o_cw = out + 336;
  float* o_att = out + 672;
  float* o_frm = out + 12672;
  float* m_ca = out + 264672;
  float* m_cw = out + 265008;
  float* m_att = out + 265344;
  float* m_frm = out + 277344;
  float* x_out = out + 529344;
  float* mu_out = out + 25105344;
  float* mup_out = out + 25367488;

  hipMemsetAsync(rowsum, 0, (768 + 352 + 352 + 12032) * sizeof(float), stream);
  k_prep<<<7264, 256, 0, stream>>>(W, Wt, ac, fg, nacf, nacb, mup, nmu, x_in, Ab);
  k_gemm<<<1504, 256, 0, stream>>>(Ab, Wt, bemb, x_out, Xb, rowsq);
  for (int it = 0; it < 5; it++) {
    bool last = (it == 4);
    k_em_pass<<<dim3(16, 32), 512, 0, stream>>>(Xb, nmu, rowsq, partial,
                                                rowsum + it * 128, nullptr);
    k_mu_finish<<<128, 256, 0, stream>>>(partial, last ? (rowsum + 4 * 128) : nullptr,
                                         nullptr, last ? mu : nullptr,
                                         last ? mu_out : nullptr, nmu);
  }
  k_em_pass<<<dim3(16, 32), 512, 0, stream>>>(Xb, nmu, rowsq, partial, rowsum + 5 * 128, z);
  k_mu_finish<<<128, 256, 0, stream>>>(partial, nullptr, accS, nullptr, nullptr, nullptr);
  k_wood_mupred<<<144, 256, 0, stream>>>(z, rowsum + 5 * 128, accS, mu, G, nmu, nacf, mup_out);
  k_rw_passC<<<dim3(16, 25), 256, 0, stream>>>(Xb, z, G, Rb, invr);
  // o-phase (on x)
  k_pred_p1<<<375, 256, 0, stream>>>(Xb, nacb, rowsq, 1, o_frm, o_att, natt, asums_o);
  k_pred_p2<<<dim3(16, 2, 8), 256, 0, stream>>>(Xb, natt, asums_o, partF);
  k_feat_finish<<<2816, 256, 0, stream>>>(partF, feats);
  k_pred_final<<<16, 256, 0, stream>>>(feats, nacf, o_ca, o_cw);
  // m-phase (on refined)
  k_pred_p1<<<375, 256, 0, stream>>>(Rb, nacb, invr, 0, m_frm, m_att, natt, asums_m);
  k_pred_p2<<<dim3(16, 2, 8), 256, 0, stream>>>(Rb, natt, asums_m, partF);
  k_feat_finish<<<2816, 256, 0, stream>>>(partF, feats);
  k_pred_final<<<16, 256, 0, stream>>>(feats, nacf, m_ca, m_cw);
}

// Round 4
// 1108.653 us; speedup vs baseline: 1.5482x; 1.0755x over previous
//
#include <hip/hip_runtime.h>

#define NB 16
#define TT 750
#define DD 2048
#define KK 8
#define CC 21
#define NT 12000

typedef __bf16 bf16;
typedef __attribute__((ext_vector_type(4))) float floatx4;
typedef __attribute__((ext_vector_type(8))) __bf16 bf16x8;
typedef __attribute__((ext_vector_type(4))) __bf16 bf16x4;

__device__ __forceinline__ float wave_allreduce_sum(float v) {
#pragma unroll
  for (int m = 32; m > 0; m >>= 1) v += __shfl_xor(v, m, 64);
  return v;
}

__device__ __forceinline__ void async_lds16(const bf16* g, bf16* l) {
  __builtin_amdgcn_global_load_lds(
      (const __attribute__((address_space(1))) void*)(g),
      (__attribute__((address_space(3))) void*)(l), 16, 0, 0);
}

// ============ fused prep: W transpose+bf16 | ac_norm | mu_norm0 | x->bf16 =======
__global__ __launch_bounds__(256) void k_prep(
    const float* __restrict__ W, bf16* __restrict__ Wt,
    const float* __restrict__ ac, const float* __restrict__ fg,
    float* __restrict__ nacf, bf16* __restrict__ nacb,
    const float* __restrict__ mup, float* __restrict__ nmu, bf16* __restrict__ nmub,
    const float* __restrict__ x, bf16* __restrict__ Ab) {
  int b = blockIdx.x, tid = threadIdx.x;
  __shared__ float tile[32][33];
  __shared__ float sb[4];
  if (b < 4096) {
    int j0 = (b & 63) * 32, k0 = (b >> 6) * 32;
    int tx = tid & 31, ty = tid >> 5;
#pragma unroll
    for (int i = 0; i < 4; i++)
      tile[ty + 8 * i][tx] = W[(size_t)(k0 + ty + 8 * i) * DD + j0 + tx];
    __syncthreads();
#pragma unroll
    for (int i = 0; i < 4; i++)
      Wt[(size_t)(j0 + ty + 8 * i) * DD + k0 + tx] = (bf16)tile[tx][ty + 8 * i];
    return;
  }
  if (b < 4128) {
    int r = b - 4096;
    int d0 = tid * 8;
    if (r >= 22) {
#pragma unroll
      for (int j = 0; j < 8; j++) nacb[(size_t)r * DD + d0 + j] = (bf16)0.f;
      return;
    }
    const float* src = (r < 21) ? (ac + (size_t)r * DD) : fg;
    float v[8];
    floatx4 a = *(const floatx4*)(src + d0);
    floatx4 c = *(const floatx4*)(src + d0 + 4);
    v[0]=a.x; v[1]=a.y; v[2]=a.z; v[3]=a.w; v[4]=c.x; v[5]=c.y; v[6]=c.z; v[7]=c.w;
    float ss = 0.f;
#pragma unroll
    for (int j = 0; j < 8; j++) ss += v[j] * v[j];
    ss = wave_allreduce_sum(ss);
    int lane = tid & 63, wid = tid >> 6;
    if (lane == 0) sb[wid] = ss;
    __syncthreads();
    float inv = 1.f / (sqrtf(sb[0] + sb[1] + sb[2] + sb[3]) + 1e-9f);
#pragma unroll
    for (int j = 0; j < 8; j++) {
      float nv = v[j] * inv;
      nacf[(size_t)r * DD + d0 + j] = nv;
      nacb[(size_t)r * DD + d0 + j] = (bf16)nv;
    }
    return;
  }
  if (b < 4256) {
    int bb = b - 4128;  // n*8+k
    int n = bb >> 3, k = bb & 7;
    int lane = tid & 63, wid = tid >> 6;
    const float* p = mup + (size_t)k * DD + tid * 8;
    float v[8];
    floatx4 a = *(const floatx4*)p;
    floatx4 c = *(const floatx4*)(p + 4);
    v[0]=a.x; v[1]=a.y; v[2]=a.z; v[3]=a.w; v[4]=c.x; v[5]=c.y; v[6]=c.z; v[7]=c.w;
    float ss = 0.f;
#pragma unroll
    for (int j = 0; j < 8; j++) ss += v[j] * v[j];
    ss = wave_allreduce_sum(ss);
    if (lane == 0) sb[wid] = ss;
    __syncthreads();
    float inv = 1.f / (sqrtf(sb[0] + sb[1] + sb[2] + sb[3]) + 1e-9f);
    float* q = nmu + (size_t)bb * DD + tid * 8;
    bf16* qb = nmub + (size_t)(n * 16 + k) * DD + tid * 8;
#pragma unroll
    for (int j = 0; j < 8; j++) {
      float nv = v[j] * inv;
      q[j] = nv;
      qb[j] = (bf16)nv;
    }
    return;
  }
  int unit0 = (b - 4256) * 4;
#pragma unroll
  for (int u = 0; u < 4; u++) {
    size_t base = ((size_t)(unit0 + u) * 256 + tid) * 8;
    int row = (int)(base >> 11);
    bf16x8 o = {};
    if (row < NT) {
      floatx4 a = *(const floatx4*)(x + base);
      floatx4 c = *(const floatx4*)(x + base + 4);
      o[0]=(bf16)a.x; o[1]=(bf16)a.y; o[2]=(bf16)a.z; o[3]=(bf16)a.w;
      o[4]=(bf16)c.x; o[5]=(bf16)c.y; o[6]=(bf16)c.z; o[7]=(bf16)c.w;
    }
    *(bf16x8*)(Ab + base) = o;
  }
}

// ============ embedding GEMM ====================================================
__global__ __launch_bounds__(256) void k_gemm(
    const bf16* __restrict__ Ab, const bf16* __restrict__ Bt,
    const float* __restrict__ bias,
    float* __restrict__ Cout, bf16* __restrict__ Cb, float* __restrict__ rowsq) {
  __shared__ bf16 As[128 * 64];
  __shared__ bf16 Bs[128 * 64];
  int tid = threadIdx.x;
  int bid = blockIdx.x;
  int xcd = bid & 7;
  int j = bid >> 3;
  int n0 = (xcd * 2 + (j >= 94 ? 1 : 0)) * 128;
  int m0 = (j % 94) * 128;
  int wid = tid >> 6, lane = tid & 63;
  int wm = (wid >> 1) * 64, wn = (wid & 1) * 64;
  int lrow = lane & 15, lko = (lane >> 4) * 8;
  int lr7 = lrow & 7;
  floatx4 acc[4][4] = {};
  int crow = tid >> 3;
  int jg = ((tid & 7) ^ (crow & 7)) * 8;
  const bf16* gA = Ab + (size_t)(m0 + crow) * DD + jg;
  const bf16* gB = Bt + (size_t)(n0 + crow) * DD + jg;
  bf16* lA = As + tid * 8;
  bf16* lB = Bs + tid * 8;
  for (int k0 = 0; k0 < DD; k0 += 64) {
#pragma unroll
    for (int s = 0; s < 4; s++)
      async_lds16(gA + (size_t)(32 * s) * DD + k0, lA + 2048 * s);
#pragma unroll
    for (int s = 0; s < 4; s++)
      async_lds16(gB + (size_t)(32 * s) * DD + k0, lB + 2048 * s);
    __syncthreads();
#pragma unroll
    for (int ks = 0; ks < 64; ks += 32) {
      bf16x8 af[4], bfr[4];
#pragma unroll
      for (int i = 0; i < 4; i++) {
        int sw = (((ks + lko) >> 3) ^ lr7) * 8;
        af[i] = *(const bf16x8*)(As + (wm + i * 16 + lrow) * 64 + sw);
      }
#pragma unroll
      for (int jj = 0; jj < 4; jj++) {
        int sw = (((ks + lko) >> 3) ^ lr7) * 8;
        bfr[jj] = *(const bf16x8*)(Bs + (wn + jj * 16 + lrow) * 64 + sw);
      }
#pragma unroll
      for (int i = 0; i < 4; i++)
#pragma unroll
        for (int jj = 0; jj < 4; jj++)
          acc[i][jj] = __builtin_amdgcn_mfma_f32_16x16x32_bf16(af[i], bfr[jj], acc[i][jj], 0, 0, 0);
    }
    __syncthreads();
  }
  int quad = lane >> 4;
  float bv[4];
#pragma unroll
  for (int jj = 0; jj < 4; jj++) bv[jj] = bias[n0 + wn + jj * 16 + lrow];
#pragma unroll
  for (int i = 0; i < 4; i++) {
#pragma unroll
    for (int r = 0; r < 4; r++) {
      int row = m0 + wm + i * 16 + quad * 4 + r;
      bool ok = (row < NT);
      float sq = 0.f;
#pragma unroll
      for (int jj = 0; jj < 4; jj++) {
        int col = n0 + wn + jj * 16 + lrow;
        float v = acc[i][jj][r] + bv[jj];
        v = fmaxf(v, 0.f);
        if (ok) {
          Cout[(size_t)row * DD + col] = v;
          Cb[(size_t)row * DD + col] = (bf16)v;
        }
        sq += v * v;
      }
#pragma unroll
      for (int m = 1; m < 16; m <<= 1) sq += __shfl_xor(sq, m, 64);
      if (ok && lrow == 0) atomicAdd(&rowsq[row], sq);
    }
  }
}

// ============ EM score pass: MFMA [64t x 16k], in-register softmax over k =======
__global__ __launch_bounds__(256) void k_score(
    const bf16* __restrict__ Xb, const bf16* __restrict__ nmub,
    const float* __restrict__ rowsq,
    float* __restrict__ z, float* __restrict__ rowsum) {
  __shared__ bf16 As[2][64 * 64];
  __shared__ bf16 Bs[2][16 * 64];
  int tid = threadIdx.x, lane = tid & 63, w = tid >> 6;
  int m0 = blockIdx.x * 64, n = blockIdx.y;
  int lrow = lane & 15, lko = (lane >> 4) * 8, lr7 = lrow & 7;
  int crow = tid >> 3;
  int jg = ((tid & 7) ^ (crow & 7)) * 8;
  const bf16* gA = Xb + (size_t)(n * TT + m0 + crow) * DD + jg;
  const bf16* gB = nmub + (size_t)(n * 16 + (crow & 15)) * DD + jg;
  async_lds16(gA, &As[0][tid * 8]);
  async_lds16(gA + (size_t)32 * DD, &As[0][2048 + tid * 8]);
  if (tid < 128) async_lds16(gB, &Bs[0][tid * 8]);
  floatx4 acc = {};
  int buf = 0;
  for (int k0 = 0; k0 < DD; k0 += 64) {
    __syncthreads();
    if (k0 + 64 < DD) {
      async_lds16(gA + k0 + 64, &As[buf ^ 1][tid * 8]);
      async_lds16(gA + (size_t)32 * DD + k0 + 64, &As[buf ^ 1][2048 + tid * 8]);
      if (tid < 128) async_lds16(gB + k0 + 64, &Bs[buf ^ 1][tid * 8]);
    }
#pragma unroll
    for (int ks = 0; ks < 64; ks += 32) {
      int sw = ((((ks + lko) >> 3)) ^ lr7) * 8;
      bf16x8 a = *(const bf16x8*)(&As[buf][(w * 16 + lrow) * 64 + sw]);
      bf16x8 b = *(const bf16x8*)(&Bs[buf][lrow * 64 + sw]);
      acc = __builtin_amdgcn_mfma_f32_16x16x32_bf16(a, b, acc, 0, 0, 0);
    }
    buf ^= 1;
  }
  int quad = lane >> 4;
  int k = lrow;
  float pacc = 0.f;
#pragma unroll
  for (int r = 0; r < 4; r++) {
    int trow = m0 + w * 16 + quad * 4 + r;
    bool valid = (trow < TT);
    float rq = valid ? rowsq[n * TT + trow] : 1.f;
    float s = acc[r] * (5.f / (sqrtf(rq) + 1e-9f));
    float mx = s;
    mx = fmaxf(mx, __shfl_xor(mx, 1, 64));
    mx = fmaxf(mx, __shfl_xor(mx, 2, 64));
    mx = fmaxf(mx, __shfl_xor(mx, 4, 64));
    float e = __expf(s - mx);
    float se = e;
    se += __shfl_xor(se, 1, 64);
    se += __shfl_xor(se, 2, 64);
    se += __shfl_xor(se, 4, 64);
    float zz = e / se;
    zz = (valid && k < 8) ? zz : 0.f;
    if (valid && k < 8) z[(size_t)(n * TT + trow) * 8 + k] = zz;
    pacc += zz;
  }
  pacc += __shfl_xor(pacc, 16, 64);
  pacc += __shfl_xor(pacc, 32, 64);
  if (lane < 8) atomicAdd(&rowsum[n * 8 + lane], pacc);
}

// ============ EM accumulate: mu_part = z @ X =====================================
__global__ __launch_bounds__(256) void k_mu_accum(
    const bf16* __restrict__ Xb, const float* __restrict__ z,
    float* __restrict__ part2) {
  int n = blockIdx.x, dt = blockIdx.y, tc = blockIdx.z, tid = threadIdx.x;
  int d = dt * 256 + tid;
  int t0 = tc * 375;
  __shared__ float zs[375 * 8];
  for (int i = tid; i < 3000; i += 256) zs[i] = z[(size_t)(n * TT + t0) * 8 + i];
  __syncthreads();
  float acc[8] = {};
  const bf16* xp = Xb + (size_t)(n * TT + t0) * DD + d;
  bf16 xg = xp[0];
  for (int tt = 0; tt < 375; tt++) {
    float xv = (float)xg;
    if (tt + 1 < 375) xg = xp[(size_t)(tt + 1) * DD];
    floatx4 za = *(const floatx4*)&zs[tt * 8];
    floatx4 zb4 = *(const floatx4*)&zs[tt * 8 + 4];
    acc[0] += za.x * xv; acc[1] += za.y * xv; acc[2] += za.z * xv; acc[3] += za.w * xv;
    acc[4] += zb4.x * xv; acc[5] += zb4.y * xv; acc[6] += zb4.z * xv; acc[7] += zb4.w * xv;
  }
  float* pb = part2 + ((size_t)(tc * 16 + n) * 8) * DD + d;
#pragma unroll
  for (int k = 0; k < 8; k++) pb[(size_t)k * DD] = acc[k];
}

// ============ EM finish =========================================================
__global__ void k_mu_finish(const float* __restrict__ part2, const float* __restrict__ rs,
                            float* __restrict__ accS_raw, float* __restrict__ mu_ws,
                            float* __restrict__ mu_out, float* __restrict__ nmu_out,
                            bf16* __restrict__ nmub) {
  int b = blockIdx.x;  // n*8+k
  int n = b >> 3, k = b & 7;
  int tid = threadIdx.x, lane = tid & 63, wid = tid >> 6;
  int d0 = tid * 8;
  const float* p0 = part2 + ((size_t)n * 8 + k) * DD + d0;
  const float* p1 = part2 + ((size_t)(16 + n) * 8 + k) * DD + d0;
  float s[8];
  {
    floatx4 a = *(const floatx4*)p0;
    floatx4 c = *(const floatx4*)(p0 + 4);
    floatx4 a2 = *(const floatx4*)p1;
    floatx4 c2 = *(const floatx4*)(p1 + 4);
    s[0]=a.x+a2.x; s[1]=a.y+a2.y; s[2]=a.z+a2.z; s[3]=a.w+a2.w;
    s[4]=c.x+c2.x; s[5]=c.y+c2.y; s[6]=c.z+c2.z; s[7]=c.w+c2.w;
  }
  if (accS_raw != nullptr) {
#pragma unroll
    for (int j = 0; j < 8; j++) accS_raw[(size_t)b * DD + d0 + j] = s[j];
    return;
  }
  float invr = 1.f / (rs[b] + 1e-9f);
  float m[8];
#pragma unroll
  for (int j = 0; j < 8; j++) m[j] = s[j] * invr;
#pragma unroll
  for (int j = 0; j < 8; j++) mu_ws[(size_t)b * DD + d0 + j] = m[j];
  if (mu_out != nullptr) {
#pragma unroll
    for (int j = 0; j < 8; j++) mu_out[(size_t)b * DD + d0 + j] = m[j];
  }
  float ss = 0.f;
#pragma unroll
  for (int j = 0; j < 8; j++) ss += m[j] * m[j];
  ss = wave_allreduce_sum(ss);
  __shared__ float sb[4];
  if (lane == 0) sb[wid] = ss;
  __syncthreads();
  float inv = 1.f / (sqrtf(sb[0] + sb[1] + sb[2] + sb[3]) + 1e-9f);
  bf16* qb = nmub + (size_t)(n * 16 + k) * DD + d0;
#pragma unroll
  for (int j = 0; j < 8; j++) {
    float nv = m[j] * inv;
    nmu_out[(size_t)b * DD + d0 + j] = nv;
    qb[j] = (bf16)nv;
  }
}

// ============ Woodbury + mu_pred ================================================
__global__ void k_wood_mupred(const float* __restrict__ z, const float* __restrict__ rowsum,
                              const float* __restrict__ S, const float* __restrict__ mu,
                              float* __restrict__ G,
                              const float* __restrict__ nmu, const float* __restrict__ nacf,
                              float* __restrict__ mupred) {
  int tid = threadIdx.x;
  if (blockIdx.x >= 16) {
    int b = blockIdx.x - 16;
    int lane = tid & 63, wid = tid >> 6;
    const float* v = nmu + (size_t)b * DD;
    __shared__ float scr[21];
    for (int c = wid; c < 21; c += 4) {
      const float* a = nacf + (size_t)c * DD;
      float s = 0.f;
      for (int i = lane * 4; i < DD; i += 256) {
        floatx4 vv = *(const floatx4*)(v + i);
        floatx4 aa = *(const floatx4*)(a + i);
        s += vv.x * aa.x + vv.y * aa.y + vv.z * aa.z + vv.w * aa.w;
      }
      s = wave_allreduce_sum(s);
      if (lane == 0) scr[c] = s * 20.f;
    }
    __syncthreads();
    if (tid == 0) {
      float mx = scr[0];
      for (int c = 1; c < 21; c++) mx = fmaxf(mx, scr[c]);
      float se = 0.f;
      for (int c = 0; c < 21; c++) se += __expf(scr[c] - mx);
      float inv = 1.f / se;
      for (int c = 0; c < 21; c++) mupred[(size_t)b * 21 + c] = __expf(scr[c] - mx) * inv;
    }
    return;
  }
  int n = blockIdx.x;
  __shared__ float VU[8][8];
  __shared__ float Mi[8][8];
  __shared__ float invrs[8];
  __shared__ float vus[64][4];
  if (tid < 8) invrs[tid] = 1.f / (rowsum[n * 8 + tid] + 1e-9f);
  {
    int pr = tid >> 2, sl = tid & 3;
    int jj = pr >> 3, kk = pr & 7;
    float s = 0.f;
    for (int t = sl; t < TT; t += 4) {
      const float* zp = z + (size_t)(n * TT + t) * 8;
      s += zp[jj] * zp[kk];
    }
    vus[pr][sl] = s;
  }
  __syncthreads();
  if (tid < 64)
    VU[tid >> 3][tid & 7] =
        (vus[tid][0] + vus[tid][1] + vus[tid][2] + vus[tid][3]) * invrs[tid >> 3];
  __syncthreads();
  if (tid == 0) {
    float M[8][16];
    for (int i = 0; i < 8; i++)
      for (int jj = 0; jj < 8; jj++) {
        M[i][jj] = ((i == jj) ? 1.f : 0.f) - 0.25f * VU[i][jj];
        M[i][8 + jj] = (i == jj) ? 1.f : 0.f;
      }
    for (int c = 0; c < 8; c++) {
      float pv = 1.f / M[c][c];
      for (int jj = 0; jj < 16; jj++) M[c][jj] *= pv;
      for (int rr = 0; rr < 8; rr++)
        if (rr != c) {
          float f = M[rr][c];
          for (int jj = 0; jj < 16; jj++) M[rr][jj] -= f * M[c][jj];
        }
    }
    for (int i = 0; i < 8; i++)
      for (int jj = 0; jj < 8; jj++) Mi[i][jj] = M[i][8 + jj];
  }
  __syncthreads();
  const float* mun = mu + (size_t)n * 8 * DD;
  const float* Sn = S + (size_t)n * 8 * DD;
  float* Gn = G + (size_t)n * 8 * DD;
  for (int d = tid; d < DD; d += 256) {
    float m[8], P[8];
#pragma unroll
    for (int k = 0; k < 8; k++) m[k] = mun[k * DD + d];
#pragma unroll
    for (int k = 0; k < 8; k++) {
      float s = 0.f;
#pragma unroll
      for (int jj = 0; jj < 8; jj++) s += VU[k][jj] * m[jj];
      P[k] = 0.5f * s + Sn[k * DD + d] * invrs[k];
    }
#pragma unroll
    for (int jj = 0; jj < 8; jj++) {
      float s = 0.f;
#pragma unroll
      for (int k = 0; k < 8; k++) s += Mi[jj][k] * P[k];
      Gn[jj * DD + d] = 0.5f * (0.5f * m[jj] + 0.25f * s);
    }
  }
}

// ============ RW pass ===========================================================
__global__ __launch_bounds__(256) void k_rw_passC(
    const bf16* __restrict__ Xb, const float* __restrict__ z,
    const float* __restrict__ G, bf16* __restrict__ refb,
    float* __restrict__ invr) {
  int n = blockIdx.x, ch = blockIdx.y, tid = threadIdx.x;
  int lane = tid & 63, wid = tid >> 6;
  int d0 = tid * 8;
  int t0 = ch * 30;
  const float* Gn = G + (size_t)n * 8 * DD;
  float gr[8][8];
#pragma unroll
  for (int k = 0; k < 8; k++) {
    floatx4 a = *(const floatx4*)(Gn + k * DD + d0);
    floatx4 b = *(const floatx4*)(Gn + k * DD + d0 + 4);
    gr[k][0]=a.x; gr[k][1]=a.y; gr[k][2]=a.z; gr[k][3]=a.w;
    gr[k][4]=b.x; gr[k][5]=b.y; gr[k][6]=b.z; gr[k][7]=b.w;
  }
  __shared__ float red[30][4];
  const bf16* xrow = Xb + (size_t)n * TT * DD;
  bf16x8 xg = *(const bf16x8*)(xrow + (size_t)t0 * DD + d0);
  for (int tt = 0; tt < 30; tt++) {
    int t = t0 + tt;
    bf16x8 x8 = xg;
    if (tt + 1 < 30) xg = *(const bf16x8*)(xrow + (size_t)(t + 1) * DD + d0);
    const float* zp = z + (size_t)(n * TT + t) * 8;
    floatx4 za = *(const floatx4*)zp;
    floatx4 zb4 = *(const floatx4*)(zp + 4);
    float zt[8] = {za.x, za.y, za.z, za.w, zb4.x, zb4.y, zb4.z, zb4.w};
    float r[8];
#pragma unroll
    for (int j = 0; j < 8; j++) {
      float s = 0.5f * (float)x8[j];
#pragma unroll
      for (int k = 0; k < 8; k++) s += zt[k] * gr[k][j];
      r[j] = s;
    }
    bf16x8 ro;
#pragma unroll
    for (int j = 0; j < 8; j++) ro[j] = (bf16)r[j];
    *(bf16x8*)(refb + (size_t)(n * TT + t) * DD + d0) = ro;
    float ss = 0.f;
#pragma unroll
    for (int j = 0; j < 8; j++) ss += r[j] * r[j];
    ss = wave_allreduce_sum(ss);
    if (lane == 0) red[tt][wid] = ss;
  }
  __syncthreads();
  if (tid < 30) {
    float tot = red[tid][0] + red[tid][1] + red[tid][2] + red[tid][3];
    invr[n * TT + t0 + tid] = 1.f / (sqrtf(tot) + 1e-9f);
  }
}

// ============ pred pass1 ========================================================
__global__ __launch_bounds__(256) void k_pred_p1(
    const bf16* __restrict__ Xb, const bf16* __restrict__ nacb,
    const float* __restrict__ invn, int mode,
    float* __restrict__ out_frm, float* __restrict__ out_att,
    float* __restrict__ natt, float* __restrict__ att_sums) {
  __shared__ bf16 As[2][2048];
  __shared__ bf16 Bs[2][2048];
  __shared__ float ssum[2][32];
  int tid = threadIdx.x, lane = tid & 63, wid = tid >> 6;
  int m0 = blockIdx.x * 32;
  if (tid < 64) ssum[tid >> 5][tid & 31] = 0.f;
  int lrow = lane & 15, lko = (lane >> 4) * 8;
  int lr7 = lrow & 7;
  int r0 = (wid & 1) * 16, c0 = (wid >> 1) * 16;
  int crow = tid >> 3;
  int jg = ((tid & 7) ^ (crow & 7)) * 8;
  const bf16* gA = Xb + (size_t)(m0 + crow) * DD + jg;
  const bf16* gB = nacb + (size_t)crow * DD + jg;
  async_lds16(gA, &As[0][tid * 8]);
  async_lds16(gB, &Bs[0][tid * 8]);
  floatx4 acc = {};
  int buf = 0;
  for (int k0 = 0; k0 < DD; k0 += 64) {
    __syncthreads();
    if (k0 + 64 < DD) {
      async_lds16(gA + k0 + 64, &As[buf ^ 1][tid * 8]);
      async_lds16(gB + k0 + 64, &Bs[buf ^ 1][tid * 8]);
    }
#pragma unroll
    for (int ks = 0; ks < 64; ks += 32) {
      int sw = ((((ks + lko) >> 3) ^ lr7)) * 8;
      bf16x8 a = *(const bf16x8*)(&As[buf][(r0 + lrow) * 64 + sw]);
      bf16x8 b = *(const bf16x8*)(&Bs[buf][(c0 + lrow) * 64 + sw]);
      acc = __builtin_amdgcn_mfma_f32_16x16x32_bf16(a, b, acc, 0, 0, 0);
    }
    buf ^= 1;
  }
  __syncthreads();
  int quad = lane >> 4;
  int nbase = m0 / TT;
  int c = c0 + lrow;
#pragma unroll
  for (int r = 0; r < 4; r++) {
    int row = m0 + r0 + quad * 4 + r;
    if (c < 22) {
      float iv = mode ? (1.f / (sqrtf(invn[row]) + 1e-9f)) : invn[row];
      float s = acc[r] * iv * 20.f;
      float sg = 1.f / (1.f + __expf(-s));
      int n_loc = row / TT - nbase;
      if (c < 21) out_frm[(size_t)row * 21 + c] = s;
      else out_att[row] = sg;
      natt[(size_t)row * 22 + c] = sg;
      atomicAdd(&ssum[n_loc][c], sg);
    }
  }
  __syncthreads();
  if (tid < 64) {
    int nl = tid >> 5, cs = tid & 31;
    int nn = nbase + nl;
    if (cs < 22 && nn < NB) {
      float v = ssum[nl][cs];
      if (v != 0.f) atomicAdd(&att_sums[nn * 22 + cs], v);
    }
  }
}

// ============ pred pass2 ========================================================
__global__ __launch_bounds__(256) void k_pred_p2(
    const bf16* __restrict__ Xb, const float* __restrict__ natt,
    const float* __restrict__ sums, float* __restrict__ partF) {
  int n = blockIdx.x, dh = blockIdx.y, tc = blockIdx.z, tid = threadIdx.x;
  int d = dh * 1024 + tid * 4;
  int t0 = tc * 94;
  int tcnt = min(94, TT - t0);
  __shared__ float sw[94 * 22];
  for (int i = tid; i < tcnt * 22; i += 256) {
    int c = i - (i / 22) * 22;
    sw[i] = natt[(size_t)(n * TT + t0) * 22 + i] / (sums[n * 22 + c] + 1e-5f);
  }
  __syncthreads();
  float ac[22][4] = {};
  const bf16* xrow = Xb + (size_t)n * TT * DD;
  bf16x4 xg = *(const bf16x4*)(xrow + (size_t)t0 * DD + d);
  for (int tt = 0; tt < tcnt; tt++) {
    bf16x4 x4 = xg;
    if (tt + 1 < tcnt) xg = *(const bf16x4*)(xrow + (size_t)(t0 + tt + 1) * DD + d);
    float xv[4] = {(float)x4[0], (float)x4[1], (float)x4[2], (float)x4[3]};
#pragma unroll
    for (int cidx = 0; cidx < 22; cidx++) {
      float w = sw[tt * 22 + cidx];
#pragma unroll
      for (int jj = 0; jj < 4; jj++) ac[cidx][jj] += w * xv[jj];
    }
  }
  float* pb = partF + ((size_t)(n * 8 + tc) * 22) * DD + d;
#pragma unroll
  for (int cidx = 0; cidx < 22; cidx++) {
    floatx4 v = {ac[cidx][0], ac[cidx][1], ac[cidx][2], ac[cidx][3]};
    *(floatx4*)(pb + (size_t)cidx * DD) = v;
  }
}

// ============ reduce feats partials =============================================
__global__ void k_feat_finish(const float* __restrict__ partF, float* __restrict__ feats) {
  int idx = blockIdx.x * 256 + threadIdx.x;
  if (idx >= NB * 22 * DD) return;
  int n = idx / (22 * DD);
  int rem = idx - n * (22 * DD);
  const float* p = partF + ((size_t)n * 8) * (22 * DD) + rem;
  float s = 0.f;
#pragma unroll
  for (int tc = 0; tc < 8; tc++) s += p[(size_t)tc * 22 * DD];
  feats[idx] = s;
}

// ============ final scores + softmax ============================================
__global__ void k_pred_final(const float* __restrict__ feats, const float* __restrict__ nacf,
                             float* __restrict__ oca, float* __restrict__ ocw) {
  int n = blockIdx.x, tid = threadIdx.x, lane = tid & 63, wid = tid >> 6;
  const float* fn = feats + (size_t)n * 22 * DD;
  __shared__ float rnorm[22];
  __shared__ float scr[42];
  for (int r = wid; r < 22; r += 4) {
    const float* fv = fn + (size_t)r * DD;
    float s = 0.f;
    for (int i = lane * 4; i < DD; i += 256) {
      floatx4 v = *(const floatx4*)(fv + i);
      s += v.x * v.x + v.y * v.y + v.z * v.z + v.w * v.w;
    }
    s = wave_allreduce_sum(s);
    if (lane == 0) rnorm[r] = 1.f / (sqrtf(s) + 1e-9f);
  }
  __syncthreads();
  for (int idx = wid; idx < 42; idx += 4) {
    int c = (idx < 21) ? idx : (idx - 21);
    int fr = (idx < 21) ? c : 21;
    const float* fv = fn + (size_t)fr * DD;
    const float* av = nacf + (size_t)c * DD;
    float s = 0.f;
    for (int i = lane * 4; i < DD; i += 256) {
      floatx4 v = *(const floatx4*)(fv + i);
      floatx4 a = *(const floatx4*)(av + i);
      s += v.x * a.x + v.y * a.y + v.z * a.z + v.w * a.w;
    }
    s = wave_allreduce_sum(s);
    if (lane == 0) scr[idx] = s * 20.f * rnorm[fr];
  }
  __syncthreads();
  if (tid < 2) {
    int base = (tid == 0) ? 21 : 0;
    float* dst = ((tid == 0) ? oca : ocw) + (size_t)n * 21;
    float mx = scr[base];
    for (int c = 1; c < 21; c++) mx = fmaxf(mx, scr[base + c]);
    float se = 0.f;
    for (int c = 0; c < 21; c++) se += __expf(scr[base + c] - mx);
    float inv = 1.f / se;
    for (int c = 0; c < 21; c++) dst[c] = __expf(scr[base + c] - mx) * inv;
  }
}

extern "C" void kernel_launch(void* const* d_in, const int* in_sizes, int n_in,
                              void* d_out, int out_size, void* d_ws, size_t ws_size,
                              hipStream_t stream) {
  const float* x_in = (const float*)d_in[0];
  const float* W = (const float*)d_in[1];
  const float* bemb = (const float*)d_in[2];
  const float* mup = (const float*)d_in[3];
  const float* ac = (const float*)d_in[4];
  const float* fg = (const float*)d_in[5];
  float* out = (float*)d_out;

  char* ws = (char*)d_ws;
  bf16* Wt = (bf16*)ws;                       // 8,388,608
  bf16* Xb = (bf16*)(ws + 8388608);           // 49,283,072 (12032 rows)
  bf16* Rb = (bf16*)(ws + 57671680);          // 49,283,072
  bf16* Ab = (bf16*)(ws + 106954752);         // 49,283,072 (alias: part2 / partF)
  float* part2 = (float*)(ws + 106954752);    // 2 MB (EM phase)
  float* partF = (float*)(ws + 106954752);    // 11.5 MB (pred phase)
  bf16* nacb = (bf16*)(ws + 156237824);       // 131,072
  float* f = (float*)(ws + 156368896);
  float* nacf = f;                       // 45,056
  float* mu = nacf + 45056;              // 262,144
  float* nmu = mu + 262144;              // 262,144
  bf16* nmub = (bf16*)(nmu + 262144);    // 262,144 floats worth (1 MB)
  float* accS = nmu + 262144 + 262144;   // 262,144
  float* G = accS + 262144;              // 262,144
  float* z = G + 262144;                 // 96,000  [n][750][8]
  float* natt = z + 96000;               // 264,000
  float* feats = natt + 264000;          // 720,896
  float* invr = feats + 720896;          // 12,032
  float* rowsum = invr + 12032;          // 768 (zeroed)
  float* asums_o = rowsum + 768;         // 352 (zeroed)
  float* asums_m = asums_o + 352;        // 352 (zeroed)
  float* rowsq = asums_m + 352;          // 12,032 (zeroed)

  float* o_ca = out;
  float* o_cw = out + 336;
  float* o_att = out + 672;
  float* o_frm = out + 12672;
  float* m_ca = out + 264672;
  float* m_cw = out + 265008;
  float* m_att = out + 265344;
  float* m_frm = out + 277344;
  float* x_out = out + 529344;
  float* mu_out = out + 25105344;
  float* mup_out = out + 25367488;

  hipMemsetAsync(rowsum, 0, (768 + 352 + 352 + 12032) * sizeof(float), stream);
  hipMemsetAsync(nmub, 0, (size_t)NB * 16 * DD * sizeof(bf16), stream);
  k_prep<<<7264, 256, 0, stream>>>(W, Wt, ac, fg, nacf, nacb, mup, nmu, nmub, x_in, Ab);
  k_gemm<<<1504, 256, 0, stream>>>(Ab, Wt, bemb, x_out, Xb, rowsq);
  for (int it = 0; it < 5; it++) {
    bool last = (it == 4);
    k_score<<<dim3(12, 16), 256, 0, stream>>>(Xb, nmub, rowsq, z, rowsum + it * 128);
    k_mu_accum<<<dim3(16, 8, 2), 256, 0, stream>>>(Xb, z, part2);
    k_mu_finish<<<128, 256, 0, stream>>>(part2, rowsum + it * 128, nullptr, mu,
                                         last ? mu_out : nullptr, nmu, nmub);
  }
  k_score<<<dim3(12, 16), 256, 0, stream>>>(Xb, nmub, rowsq, z, rowsum + 5 * 128);
  k_mu_accum<<<dim3(16, 8, 2), 256, 0, stream>>>(Xb, z, part2);
  k_mu_finish<<<128, 256, 0, stream>>>(part2, nullptr, accS, nullptr, nullptr, nullptr, nullptr);
  k_wood_mupred<<<144, 256, 0, stream>>>(z, rowsum + 5 * 128, accS, mu, G, nmu, nacf, mup_out);
  k_rw_passC<<<dim3(16, 25), 256, 0, stream>>>(Xb, z, G, Rb, invr);
  // o-phase (on x)
  k_pred_p1<<<375, 256, 0, stream>>>(Xb, nacb, rowsq, 1, o_frm, o_att, natt, asums_o);
  k_pred_p2<<<dim3(16, 2, 8), 256, 0, stream>>>(Xb, natt, asums_o, partF);
  k_feat_finish<<<2816, 256, 0, stream>>>(partF, feats);
  k_pred_final<<<16, 256, 0, stream>>>(feats, nacf, o_ca, o_cw);
  // m-phase (on refined)
  k_pred_p1<<<375, 256, 0, stream>>>(Rb, nacb, invr, 0, m_frm, m_att, natt, asums_m);
  k_pred_p2<<<dim3(16, 2, 8), 256, 0, stream>>>(Rb, natt, asums_m, partF);
  k_feat_finish<<<2816, 256, 0, stream>>>(partF, feats);
  k_pred_final<<<16, 256, 0, stream>>>(feats, nacf, m_ca, m_cw);
}